// Round 1
// baseline (282.442 us; speedup 1.0000x reference)
//
#include <hip/hip_runtime.h>

#define NN 4096
#define DD 512
#define HH 8
#define DHH 64

typedef __attribute__((ext_vector_type(8))) __bf16 bfrag;
typedef __attribute__((ext_vector_type(8))) short short8;
typedef __attribute__((ext_vector_type(4))) float f32x4;
typedef unsigned int uint32;

// f32 -> bf16 round-to-nearest-even (manual; avoids header type issues)
__device__ __forceinline__ unsigned short f2b(float f) {
    unsigned int u = __builtin_bit_cast(unsigned int, f);
    unsigned int r = 0x7fffu + ((u >> 16) & 1u);
    return (unsigned short)((u + r) >> 16);
}

__device__ __forceinline__ float fexp2(float x) {
#if __has_builtin(__builtin_amdgcn_exp2f)
    return __builtin_amdgcn_exp2f(x);
#else
    return exp2f(x);
#endif
}

// ---------------- weight convert ----------------
__global__ __launch_bounds__(256) void cvt_bf16(const float* __restrict__ in,
                                                unsigned short* __restrict__ out, int n) {
    int i = blockIdx.x * 256 + threadIdx.x;
    if (i < n) out[i] = f2b(in[i]);
}

// ---------------- edge dtype detect (int64 vs int32) ----------------
// int64 layout: odd int32 words are high halves == 0 (values < 4096).
// int32 layout: odd words are random edge values -> almost surely nonzero.
__global__ void detect_i32(const int* __restrict__ ei32, int* __restrict__ flag) {
    __shared__ int any;
    if (threadIdx.x == 0) any = 0;
    __syncthreads();
    for (int i = threadIdx.x; i < 1024; i += 256)
        if (ei32[2 * i + 1] != 0) atomicOr(&any, 1);
    __syncthreads();
    if (threadIdx.x == 0) *flag = any;  // 1 -> int32 format, 0 -> int64
}

__device__ __forceinline__ void load_edge(const void* ei, int E, int i, int is32,
                                          int& r, int& c) {
    if (is32) {
        const int* p = (const int*)ei;
        r = p[i]; c = p[E + i];
    } else {
        const long long* p = (const long long*)ei;
        r = (int)p[i]; c = (int)p[E + i];
    }
}

// ---------------- adjacency build (deduped CSR) ----------------
__global__ __launch_bounds__(256) void adj_count(const void* __restrict__ ei,
                                                 const int* __restrict__ flag,
                                                 uint32* __restrict__ mask,
                                                 uint32* __restrict__ counts, int E) {
    int tid = blockIdx.x * 256 + threadIdx.x;
    int total = E + NN;
    if (tid >= total) return;
    int is32 = *flag;
    int r, c;
    if (tid < E) load_edge(ei, E, tid, is32, r, c);
    else { r = tid - E; c = r; }
    uint32 bit = 1u << (c & 31);
    uint32 old = atomicOr(&mask[r * 128 + (c >> 5)], bit);
    if (!(old & bit)) atomicAdd(&counts[r], 1u);
}

__global__ __launch_bounds__(256) void adj_fill(const void* __restrict__ ei,
                                                const int* __restrict__ flag,
                                                uint32* __restrict__ mask2,
                                                uint32* __restrict__ cursor,
                                                int* __restrict__ cols, int E) {
    int tid = blockIdx.x * 256 + threadIdx.x;
    int total = E + NN;
    if (tid >= total) return;
    int is32 = *flag;
    int r, c;
    if (tid < E) load_edge(ei, E, tid, is32, r, c);
    else { r = tid - E; c = r; }
    uint32 bit = 1u << (c & 31);
    uint32 old = atomicOr(&mask2[r * 128 + (c >> 5)], bit);
    if (!(old & bit)) {
        uint32 pos = atomicAdd(&cursor[r], 1u);
        cols[pos] = c;
    }
}

// exclusive scan over 4096 counts, one block of 1024 threads (4 each)
__global__ __launch_bounds__(1024) void scan_rows(const uint32* __restrict__ counts,
                                                  uint32* __restrict__ starts,
                                                  uint32* __restrict__ cursor) {
    __shared__ uint32 tsum[1024];
    int tid = threadIdx.x;
    uint32 c0 = counts[tid * 4], c1 = counts[tid * 4 + 1];
    uint32 c2 = counts[tid * 4 + 2], c3 = counts[tid * 4 + 3];
    tsum[tid] = c0 + c1 + c2 + c3;
    __syncthreads();
    for (int d = 1; d < 1024; d <<= 1) {
        uint32 add = (tid >= d) ? tsum[tid - d] : 0u;
        __syncthreads();
        tsum[tid] += add;
        __syncthreads();
    }
    uint32 base = (tid > 0) ? tsum[tid - 1] : 0u;
    uint32 s0 = base, s1 = base + c0, s2 = s1 + c1, s3 = s2 + c2;
    starts[tid * 4] = s0; starts[tid * 4 + 1] = s1;
    starts[tid * 4 + 2] = s2; starts[tid * 4 + 3] = s3;
    cursor[tid * 4] = s0; cursor[tid * 4 + 1] = s1;
    cursor[tid * 4 + 2] = s2; cursor[tid * 4 + 3] = s3;
}

// ---------------- layernorm: f32 row -> bf16 row ----------------
__global__ __launch_bounds__(256) void ln_rows(const float* __restrict__ x,
                                               const float* __restrict__ w,
                                               const float* __restrict__ b,
                                               unsigned short* __restrict__ out) {
    const int row = blockIdx.x;
    const int tid = threadIdx.x;
    float2 v = reinterpret_cast<const float2*>(x + (size_t)row * DD)[tid];
    float s = v.x + v.y;
    float s2 = v.x * v.x + v.y * v.y;
#pragma unroll
    for (int d = 1; d < 64; d <<= 1) {
        s += __shfl_xor(s, d);
        s2 += __shfl_xor(s2, d);
    }
    __shared__ float red[8];
    if ((tid & 63) == 0) { red[tid >> 6] = s; red[4 + (tid >> 6)] = s2; }
    __syncthreads();
    s = red[0] + red[1] + red[2] + red[3];
    s2 = red[4] + red[5] + red[6] + red[7];
    const float mean = s * (1.f / DD);
    const float var = fmaxf(s2 * (1.f / DD) - mean * mean, 0.f);
    const float rs = rsqrtf(var + 1e-5f);
    const int c = tid * 2;
    out[(size_t)row * DD + c]     = f2b((v.x - mean) * rs * w[c] + b[c]);
    out[(size_t)row * DD + c + 1] = f2b((v.y - mean) * rs * w[c + 1] + b[c + 1]);
}

// ---------------- bf16 MFMA GEMM: C[M][N] = A[M][K] @ B[N][K]^T ----------------
// tile 128x128, BK=64, 256 threads (4 waves, 2x2), 16x16x32 bf16 MFMA.
// EPI 0: QKV  -> q_out (scaled by log2e/8), k_out, v_out as f32 [H][N][64]
// EPI 1: out_f[gr*512+gc] = acc + bias + resid         (attn_out + x)
// EPI 2: out_b[gr*2048+gc] = bf16(relu(acc + bias))    (MLP hidden)
// EPI 3: out_f[gr*512+gc] = acc + bias + resid         (final)
template <int EPI>
__global__ __launch_bounds__(256) void gemm_bt(const unsigned short* __restrict__ A,
                                               const unsigned short* __restrict__ B,
                                               int K,
                                               const float* __restrict__ bias,
                                               const float* __restrict__ resid,
                                               float* __restrict__ out_f,
                                               unsigned short* __restrict__ out_b,
                                               float* __restrict__ q_out,
                                               float* __restrict__ k_out,
                                               float* __restrict__ v_out) {
    __shared__ __align__(16) unsigned short a_lds[128 * 72];
    __shared__ __align__(16) unsigned short b_lds[128 * 72];
    const int tid = threadIdx.x;
    const int lane = tid & 63;
    const int wave = tid >> 6;
    const int wm = wave >> 1, wn = wave & 1;
    const int tm = blockIdx.y, tn = blockIdx.x;

    f32x4 acc[4][4];
#pragma unroll
    for (int mi = 0; mi < 4; ++mi)
#pragma unroll
        for (int ni = 0; ni < 4; ++ni) acc[mi][ni] = (f32x4){0.f, 0.f, 0.f, 0.f};

    const size_t a_base = (size_t)(tm * 128) * K;
    const size_t b_base = (size_t)(tn * 128) * K;

    for (int k0 = 0; k0 < K; k0 += 64) {
        __syncthreads();
#pragma unroll
        for (int it = 0; it < 4; ++it) {
            int slot = tid + 256 * it;     // 0..1023
            int row = slot >> 3;           // 0..127
            int cs = (slot & 7) << 3;      // 0..56
            short8 va = *reinterpret_cast<const short8*>(A + a_base + (size_t)row * K + k0 + cs);
            short8 vb = *reinterpret_cast<const short8*>(B + b_base + (size_t)row * K + k0 + cs);
            *reinterpret_cast<short8*>(&a_lds[row * 72 + cs]) = va;
            *reinterpret_cast<short8*>(&b_lds[row * 72 + cs]) = vb;
        }
        __syncthreads();
#pragma unroll
        for (int ks = 0; ks < 2; ++ks) {
            const int kc = ((lane >> 4) << 3) + (ks << 5);
            bfrag af[4], bfr[4];
#pragma unroll
            for (int mi = 0; mi < 4; ++mi)
                af[mi] = *reinterpret_cast<const bfrag*>(
                    &a_lds[(wm * 64 + mi * 16 + (lane & 15)) * 72 + kc]);
#pragma unroll
            for (int ni = 0; ni < 4; ++ni)
                bfr[ni] = *reinterpret_cast<const bfrag*>(
                    &b_lds[(wn * 64 + ni * 16 + (lane & 15)) * 72 + kc]);
#pragma unroll
            for (int mi = 0; mi < 4; ++mi)
#pragma unroll
                for (int ni = 0; ni < 4; ++ni)
                    acc[mi][ni] = __builtin_amdgcn_mfma_f32_16x16x32_bf16(
                        af[mi], bfr[ni], acc[mi][ni], 0, 0, 0);
        }
    }

    const int r0 = (lane >> 4) << 2;
    const int cl = lane & 15;
#pragma unroll
    for (int mi = 0; mi < 4; ++mi) {
#pragma unroll
        for (int ni = 0; ni < 4; ++ni) {
#pragma unroll
            for (int r = 0; r < 4; ++r) {
                int gr = tm * 128 + wm * 64 + mi * 16 + r0 + r;
                int gc = tn * 128 + wn * 64 + ni * 16 + cl;
                float v = acc[mi][ni][r] + bias[gc];
                if (EPI == 0) {
                    if (gc < 512) {
                        // fold score scale (1/sqrt(64)) and log2(e) into q
                        q_out[((size_t)((gc >> 6) * NN) + gr) * 64 + (gc & 63)] =
                            v * 0.18033688011112042f;
                    } else if (gc < 1024) {
                        int j = gc - 512;
                        k_out[((size_t)((j >> 6) * NN) + gr) * 64 + (j & 63)] = v;
                    } else {
                        int j = gc - 1024;
                        v_out[((size_t)((j >> 6) * NN) + gr) * 64 + (j & 63)] = v;
                    }
                } else if (EPI == 1) {
                    out_f[(size_t)gr * 512 + gc] = v + resid[(size_t)gr * 512 + gc];
                } else if (EPI == 2) {
                    out_b[(size_t)gr * 2048 + gc] = f2b(fmaxf(v, 0.f));
                } else {
                    out_f[(size_t)gr * 512 + gc] = v + resid[(size_t)gr * 512 + gc];
                }
            }
        }
    }
}

// ---------------- sparse masked attention ----------------
// one wave per (head, query row); exact f32 online softmax over ~33 neighbors.
// q was pre-scaled by log2(e)/8, so probabilities are exp2(s - m).
__global__ __launch_bounds__(256) void attn_sparse(const float* __restrict__ qf,
                                                   const float* __restrict__ kf,
                                                   const float* __restrict__ vf,
                                                   const int* __restrict__ cols,
                                                   const uint32* __restrict__ starts,
                                                   const uint32* __restrict__ counts,
                                                   unsigned short* __restrict__ o_buf) {
    __shared__ __align__(16) float qs[4][64];
    const int lane = threadIdx.x & 63;
    const int wid = threadIdx.x >> 6;
    const int gw = blockIdx.x * 4 + wid;
    const int h = gw >> 12;         // / 4096
    const int q = gw & (NN - 1);
    qs[wid][lane] = qf[((size_t)h * NN + q) * DHH + lane];
    __syncthreads();
    const int cnt = (int)counts[q];
    const int base = (int)starts[q];
    const float* kh = kf + (size_t)h * NN * DHH;
    const float* vh = vf + (size_t)h * NN * DHH;
    float m_run = -3.0e38f, l_run = 0.f, o = 0.f;
    for (int p0 = 0; p0 < cnt; p0 += 64) {
        const int j = p0 + lane;
        const bool act = j < cnt;
        const int col = act ? cols[base + j] : 0;
        const float4* kr = reinterpret_cast<const float4*>(kh + (size_t)col * DHH);
        const float4* qr = reinterpret_cast<const float4*>(qs[wid]);
        float s = 0.f;
#pragma unroll
        for (int t = 0; t < 16; ++t) {
            float4 kv = kr[t];
            float4 qv = qr[t];
            s = fmaf(kv.x, qv.x, s);
            s = fmaf(kv.y, qv.y, s);
            s = fmaf(kv.z, qv.z, s);
            s = fmaf(kv.w, qv.w, s);
        }
        s = act ? s : -3.0e38f;
        float mp = s;
#pragma unroll
        for (int d = 1; d < 64; d <<= 1) mp = fmaxf(mp, __shfl_xor(mp, d));
        const float m_new = fmaxf(m_run, mp);
        const float alpha = fexp2(m_run - m_new);
        const float p = act ? fexp2(s - m_new) : 0.f;
        float ps = p;
#pragma unroll
        for (int d = 1; d < 64; d <<= 1) ps += __shfl_xor(ps, d);
        l_run = l_run * alpha + ps;
        o *= alpha;
        const int lim = min(64, cnt - p0);
        for (int jj = 0; jj < lim; ++jj) {
            const float pj = __shfl(p, jj);
            const int cj = __shfl(col, jj);
            o = fmaf(pj, vh[(size_t)cj * DHH + lane], o);
        }
        m_run = m_new;
    }
    o_buf[(size_t)q * DD + h * DHH + lane] = f2b(o / l_run);
}

// ---------------- launch ----------------
extern "C" void kernel_launch(void* const* d_in, const int* in_sizes, int n_in,
                              void* d_out, int out_size, void* d_ws, size_t ws_size,
                              hipStream_t stream) {
    const float* x = (const float*)d_in[0];
    const void* ei = d_in[1];
    const float* ln1w = (const float*)d_in[2];
    const float* ln1b = (const float*)d_in[3];
    const float* w_in = (const float*)d_in[4];
    const float* b_in = (const float*)d_in[5];
    const float* w_out = (const float*)d_in[6];
    const float* b_out = (const float*)d_in[7];
    const float* ln2w = (const float*)d_in[8];
    const float* ln2b = (const float*)d_in[9];
    const float* w1 = (const float*)d_in[10];
    const float* b1 = (const float*)d_in[11];
    const float* w2 = (const float*)d_in[12];
    const float* b2 = (const float*)d_in[13];
    float* out = (float*)d_out;
    const int E = in_sizes[1] / 2;

    char* ws = (char*)d_ws;
    size_t off = 0;
    auto alloc = [&](size_t bytes) -> void* {
        void* p = ws + off;
        off = (off + bytes + 255) & ~(size_t)255;
        return p;
    };
    uint32* mask1 = (uint32*)alloc((size_t)NN * 128 * 4);   // 2 MiB
    uint32* mask2 = (uint32*)alloc((size_t)NN * 128 * 4);   // 2 MiB
    uint32* counts = (uint32*)alloc((size_t)NN * 4);
    uint32* starts = (uint32*)alloc((size_t)NN * 4);
    uint32* cursor = (uint32*)alloc((size_t)NN * 4);
    int* flag = (int*)alloc(256);
    int* cols = (int*)alloc((size_t)(E + NN) * 4);
    unsigned short* w_in_b = (unsigned short*)alloc((size_t)1536 * 512 * 2);
    unsigned short* w_out_b = (unsigned short*)alloc((size_t)512 * 512 * 2);
    unsigned short* w1_b = (unsigned short*)alloc((size_t)2048 * 512 * 2);
    unsigned short* w2_b = (unsigned short*)alloc((size_t)512 * 2048 * 2);
    unsigned short* xn = (unsigned short*)alloc((size_t)NN * DD * 2);
    float* q_f = (float*)alloc((size_t)NN * DD * 4);        // 8 MiB
    float* k_f = (float*)alloc((size_t)NN * DD * 4);        // 8 MiB (contiguous after q_f)
    float* v_f = (float*)alloc((size_t)NN * DD * 4);
    unsigned short* o_buf = (unsigned short*)alloc((size_t)NN * DD * 2);
    float* x1 = (float*)alloc((size_t)NN * DD * 4);
    unsigned short* xm = (unsigned short*)alloc((size_t)NN * DD * 2);
    // MLP hidden [4096][2048] bf16 (16 MiB) aliases q_f+k_f (dead after attention)
    unsigned short* h_buf = (unsigned short*)q_f;

    hipMemsetAsync(mask1, 0, (size_t)NN * 128 * 4, stream);
    hipMemsetAsync(mask2, 0, (size_t)NN * 128 * 4, stream);
    hipMemsetAsync(counts, 0, (size_t)NN * 4, stream);

    cvt_bf16<<<(1536 * 512 + 255) / 256, 256, 0, stream>>>(w_in, w_in_b, 1536 * 512);
    cvt_bf16<<<(512 * 512 + 255) / 256, 256, 0, stream>>>(w_out, w_out_b, 512 * 512);
    cvt_bf16<<<(2048 * 512 + 255) / 256, 256, 0, stream>>>(w1, w1_b, 2048 * 512);
    cvt_bf16<<<(512 * 2048 + 255) / 256, 256, 0, stream>>>(w2, w2_b, 512 * 2048);

    detect_i32<<<1, 256, 0, stream>>>((const int*)ei, flag);

    const int tot = E + NN;
    adj_count<<<(tot + 255) / 256, 256, 0, stream>>>(ei, flag, mask1, counts, E);
    ln_rows<<<NN, 256, 0, stream>>>(x, ln1w, ln1b, xn);
    scan_rows<<<1, 1024, 0, stream>>>(counts, starts, cursor);
    adj_fill<<<(tot + 255) / 256, 256, 0, stream>>>(ei, flag, mask2, cursor, cols, E);

    // QKV: [4096,512] @ [1536,512]^T
    gemm_bt<0><<<dim3(12, 32), 256, 0, stream>>>(xn, w_in_b, 512, b_in, nullptr,
                                                 nullptr, nullptr, q_f, k_f, v_f);
    attn_sparse<<<NN * HH / 4, 256, 0, stream>>>(q_f, k_f, v_f, cols, starts, counts, o_buf);
    // attn_out + residual: x1 = x + o @ w_out^T + b_out
    gemm_bt<1><<<dim3(4, 32), 256, 0, stream>>>(o_buf, w_out_b, 512, b_out, x, x1,
                                                nullptr, nullptr, nullptr, nullptr);
    ln_rows<<<NN, 256, 0, stream>>>(x1, ln2w, ln2b, xm);
    // MLP1: relu(xm @ w1^T + b1) -> h (bf16)
    gemm_bt<2><<<dim3(16, 32), 256, 0, stream>>>(xm, w1_b, 512, b1, nullptr, nullptr,
                                                 h_buf, nullptr, nullptr, nullptr);
    // MLP2: out = x1 + h @ w2^T + b2
    gemm_bt<3><<<dim3(4, 32), 256, 0, stream>>>(h_buf, w2_b, 2048, b2, x1, out,
                                                nullptr, nullptr, nullptr, nullptr);
}

// Round 2
// 209.629 us; speedup vs baseline: 1.3473x; 1.3473x over previous
//
#include <hip/hip_runtime.h>

#define NN 4096
#define DD 512
#define HH 8
#define DHH 64

typedef __attribute__((ext_vector_type(8))) __bf16 bfrag;
typedef __attribute__((ext_vector_type(8))) short short8;
typedef __attribute__((ext_vector_type(4))) float f32x4;
typedef unsigned int uint32;

// f32 -> bf16 round-to-nearest-even
__device__ __forceinline__ unsigned short f2b(float f) {
    unsigned int u = __builtin_bit_cast(unsigned int, f);
    unsigned int r = 0x7fffu + ((u >> 16) & 1u);
    return (unsigned short)((u + r) >> 16);
}

__device__ __forceinline__ float b2f(unsigned short u) {
    return __builtin_bit_cast(float, (unsigned int)u << 16);
}

__device__ __forceinline__ float fexp2(float x) {
#if __has_builtin(__builtin_amdgcn_exp2f)
    return __builtin_amdgcn_exp2f(x);
#else
    return exp2f(x);
#endif
}

// ---------------- weight convert ----------------
__global__ __launch_bounds__(256) void cvt_bf16(const float* __restrict__ in,
                                                unsigned short* __restrict__ out, int n) {
    int i = blockIdx.x * 256 + threadIdx.x;
    if (i < n) out[i] = f2b(in[i]);
}

// ---------------- edge dtype detect (int64 vs int32) ----------------
__global__ void detect_i32(const int* __restrict__ ei32, int* __restrict__ flag) {
    __shared__ int any;
    if (threadIdx.x == 0) any = 0;
    __syncthreads();
    for (int i = threadIdx.x; i < 1024; i += 256)
        if (ei32[2 * i + 1] != 0) atomicOr(&any, 1);
    __syncthreads();
    if (threadIdx.x == 0) *flag = any;  // 1 -> int32 format, 0 -> int64
}

__device__ __forceinline__ void load_edge(const void* ei, int E, int i, int is32,
                                          int& r, int& c) {
    if (is32) {
        const int* p = (const int*)ei;
        r = p[i]; c = p[E + i];
    } else {
        const long long* p = (const long long*)ei;
        r = (int)p[i]; c = (int)p[E + i];
    }
}

// ---------------- adjacency build (deduped CSR) ----------------
__global__ __launch_bounds__(256) void adj_count(const void* __restrict__ ei,
                                                 const int* __restrict__ flag,
                                                 uint32* __restrict__ mask,
                                                 uint32* __restrict__ counts, int E) {
    int tid = blockIdx.x * 256 + threadIdx.x;
    int total = E + NN;
    if (tid >= total) return;
    int is32 = *flag;
    int r, c;
    if (tid < E) load_edge(ei, E, tid, is32, r, c);
    else { r = tid - E; c = r; }
    uint32 bit = 1u << (c & 31);
    uint32 old = atomicOr(&mask[r * 128 + (c >> 5)], bit);
    if (!(old & bit)) atomicAdd(&counts[r], 1u);
}

__global__ __launch_bounds__(256) void adj_fill(const void* __restrict__ ei,
                                                const int* __restrict__ flag,
                                                uint32* __restrict__ mask2,
                                                uint32* __restrict__ cursor,
                                                int* __restrict__ cols, int E) {
    int tid = blockIdx.x * 256 + threadIdx.x;
    int total = E + NN;
    if (tid >= total) return;
    int is32 = *flag;
    int r, c;
    if (tid < E) load_edge(ei, E, tid, is32, r, c);
    else { r = tid - E; c = r; }
    uint32 bit = 1u << (c & 31);
    uint32 old = atomicOr(&mask2[r * 128 + (c >> 5)], bit);
    if (!(old & bit)) {
        uint32 pos = atomicAdd(&cursor[r], 1u);
        cols[pos] = c;
    }
}

// exclusive scan over 4096 counts
__global__ __launch_bounds__(1024) void scan_rows(const uint32* __restrict__ counts,
                                                  uint32* __restrict__ starts,
                                                  uint32* __restrict__ cursor) {
    __shared__ uint32 tsum[1024];
    int tid = threadIdx.x;
    uint32 c0 = counts[tid * 4], c1 = counts[tid * 4 + 1];
    uint32 c2 = counts[tid * 4 + 2], c3 = counts[tid * 4 + 3];
    tsum[tid] = c0 + c1 + c2 + c3;
    __syncthreads();
    for (int d = 1; d < 1024; d <<= 1) {
        uint32 add = (tid >= d) ? tsum[tid - d] : 0u;
        __syncthreads();
        tsum[tid] += add;
        __syncthreads();
    }
    uint32 base = (tid > 0) ? tsum[tid - 1] : 0u;
    uint32 s0 = base, s1 = base + c0, s2 = s1 + c1, s3 = s2 + c2;
    starts[tid * 4] = s0; starts[tid * 4 + 1] = s1;
    starts[tid * 4 + 2] = s2; starts[tid * 4 + 3] = s3;
    cursor[tid * 4] = s0; cursor[tid * 4 + 1] = s1;
    cursor[tid * 4 + 2] = s2; cursor[tid * 4 + 3] = s3;
}

// ---------------- layernorm: f32 row -> bf16 row ----------------
__global__ __launch_bounds__(256) void ln_rows(const float* __restrict__ x,
                                               const float* __restrict__ w,
                                               const float* __restrict__ b,
                                               unsigned short* __restrict__ out) {
    const int row = blockIdx.x;
    const int tid = threadIdx.x;
    float2 v = reinterpret_cast<const float2*>(x + (size_t)row * DD)[tid];
    float s = v.x + v.y;
    float s2 = v.x * v.x + v.y * v.y;
#pragma unroll
    for (int d = 1; d < 64; d <<= 1) {
        s += __shfl_xor(s, d);
        s2 += __shfl_xor(s2, d);
    }
    __shared__ float red[8];
    if ((tid & 63) == 0) { red[tid >> 6] = s; red[4 + (tid >> 6)] = s2; }
    __syncthreads();
    s = red[0] + red[1] + red[2] + red[3];
    s2 = red[4] + red[5] + red[6] + red[7];
    const float mean = s * (1.f / DD);
    const float var = fmaxf(s2 * (1.f / DD) - mean * mean, 0.f);
    const float rs = rsqrtf(var + 1e-5f);
    const int c = tid * 2;
    out[(size_t)row * DD + c]     = f2b((v.x - mean) * rs * w[c] + b[c]);
    out[(size_t)row * DD + c + 1] = f2b((v.y - mean) * rs * w[c + 1] + b[c + 1]);
}

// ---------------- bf16 MFMA GEMM: C[M][N] = A[M][K] @ B[N][K]^T ----------------
template <int EPI>
__global__ __launch_bounds__(256) void gemm_bt(const unsigned short* __restrict__ A,
                                               const unsigned short* __restrict__ B,
                                               int K,
                                               const float* __restrict__ bias,
                                               const float* __restrict__ resid,
                                               float* __restrict__ out_f,
                                               unsigned short* __restrict__ out_b,
                                               float* __restrict__ q_out,
                                               unsigned short* __restrict__ k_out,
                                               unsigned short* __restrict__ v_out) {
    __shared__ __align__(16) unsigned short a_lds[128 * 72];
    __shared__ __align__(16) unsigned short b_lds[128 * 72];
    const int tid = threadIdx.x;
    const int lane = tid & 63;
    const int wave = tid >> 6;
    const int wm = wave >> 1, wn = wave & 1;
    const int tm = blockIdx.y, tn = blockIdx.x;

    f32x4 acc[4][4];
#pragma unroll
    for (int mi = 0; mi < 4; ++mi)
#pragma unroll
        for (int ni = 0; ni < 4; ++ni) acc[mi][ni] = (f32x4){0.f, 0.f, 0.f, 0.f};

    const size_t a_base = (size_t)(tm * 128) * K;
    const size_t b_base = (size_t)(tn * 128) * K;

    for (int k0 = 0; k0 < K; k0 += 64) {
        __syncthreads();
#pragma unroll
        for (int it = 0; it < 4; ++it) {
            int slot = tid + 256 * it;
            int row = slot >> 3;
            int cs = (slot & 7) << 3;
            short8 va = *reinterpret_cast<const short8*>(A + a_base + (size_t)row * K + k0 + cs);
            short8 vb = *reinterpret_cast<const short8*>(B + b_base + (size_t)row * K + k0 + cs);
            *reinterpret_cast<short8*>(&a_lds[row * 72 + cs]) = va;
            *reinterpret_cast<short8*>(&b_lds[row * 72 + cs]) = vb;
        }
        __syncthreads();
#pragma unroll
        for (int ks = 0; ks < 2; ++ks) {
            const int kc = ((lane >> 4) << 3) + (ks << 5);
            bfrag af[4], bfr[4];
#pragma unroll
            for (int mi = 0; mi < 4; ++mi)
                af[mi] = *reinterpret_cast<const bfrag*>(
                    &a_lds[(wm * 64 + mi * 16 + (lane & 15)) * 72 + kc]);
#pragma unroll
            for (int ni = 0; ni < 4; ++ni)
                bfr[ni] = *reinterpret_cast<const bfrag*>(
                    &b_lds[(wn * 64 + ni * 16 + (lane & 15)) * 72 + kc]);
#pragma unroll
            for (int mi = 0; mi < 4; ++mi)
#pragma unroll
                for (int ni = 0; ni < 4; ++ni)
                    acc[mi][ni] = __builtin_amdgcn_mfma_f32_16x16x32_bf16(
                        af[mi], bfr[ni], acc[mi][ni], 0, 0, 0);
        }
    }

    const int r0 = (lane >> 4) << 2;
    const int cl = lane & 15;
#pragma unroll
    for (int mi = 0; mi < 4; ++mi) {
#pragma unroll
        for (int ni = 0; ni < 4; ++ni) {
#pragma unroll
            for (int r = 0; r < 4; ++r) {
                int gr = tm * 128 + wm * 64 + mi * 16 + r0 + r;
                int gc = tn * 128 + wn * 64 + ni * 16 + cl;
                float v = acc[mi][ni][r] + bias[gc];
                if (EPI == 0) {
                    if (gc < 512) {
                        // fold score scale (1/sqrt(64)) and log2(e) into q
                        q_out[((size_t)((gc >> 6) * NN) + gr) * 64 + (gc & 63)] =
                            v * 0.18033688011112042f;
                    } else if (gc < 1024) {
                        int j = gc - 512;
                        k_out[((size_t)((j >> 6) * NN) + gr) * 64 + (j & 63)] = f2b(v);
                    } else {
                        int j = gc - 1024;
                        v_out[((size_t)((j >> 6) * NN) + gr) * 64 + (j & 63)] = f2b(v);
                    }
                } else if (EPI == 1) {
                    out_f[(size_t)gr * 512 + gc] = v + resid[(size_t)gr * 512 + gc];
                } else if (EPI == 2) {
                    out_b[(size_t)gr * 2048 + gc] = f2b(fmaxf(v, 0.f));
                } else {
                    out_f[(size_t)gr * 512 + gc] = v + resid[(size_t)gr * 512 + gc];
                }
            }
        }
    }
}

// ---------------- sparse masked attention (16-lane groups, 4 neighbors/step) ----
// wave per (head, query). group g = lane>>4 handles neighbor p0+g; lanes t=lane&15
// cooperatively read the 64-elem bf16 K/V row (ushort4 each -> coalesced).
// q pre-scaled by log2(e)/8, so probabilities are exp2(s - m).
__global__ __launch_bounds__(256) void attn_sparse(const float* __restrict__ qf,
                                                   const unsigned short* __restrict__ kb,
                                                   const unsigned short* __restrict__ vb,
                                                   const int* __restrict__ cols,
                                                   const uint32* __restrict__ starts,
                                                   const uint32* __restrict__ counts,
                                                   unsigned short* __restrict__ o_buf) {
    const int lane = threadIdx.x & 63;
    const int wid = threadIdx.x >> 6;
    const int gw = blockIdx.x * 4 + wid;
    const int h = gw >> 12;         // / 4096
    const int q = gw & (NN - 1);
    const int g = lane >> 4;        // neighbor group 0..3
    const int t = lane & 15;        // dim slot: dims [4t, 4t+4)

    const float4 qv = *reinterpret_cast<const float4*>(
        qf + ((size_t)h * NN + q) * DHH + t * 4);

    const int cnt = (int)counts[q];
    const int base = (int)starts[q];
    const unsigned short* kh = kb + (size_t)h * NN * DHH;
    const unsigned short* vh = vb + (size_t)h * NN * DHH;

    float m_run = -3.0e38f, l_run = 0.f;
    float4 oa = {0.f, 0.f, 0.f, 0.f};

    for (int p0 = 0; p0 < cnt; p0 += 4) {
        const int j = p0 + g;
        const bool act = j < cnt;
        const int col = act ? cols[base + j] : 0;
        const size_t roff = (size_t)col * DHH + t * 4;

        ushort4 kq = *reinterpret_cast<const ushort4*>(kh + roff);
        ushort4 vq = *reinterpret_cast<const ushort4*>(vh + roff);

        float s = qv.x * b2f(kq.x) + qv.y * b2f(kq.y) + qv.z * b2f(kq.z) + qv.w * b2f(kq.w);
        // reduce within 16-lane group
        s += __shfl_xor(s, 1);
        s += __shfl_xor(s, 2);
        s += __shfl_xor(s, 4);
        s += __shfl_xor(s, 8);
        s = act ? s : -3.0e38f;
        // max across the 4 groups
        float mp = fmaxf(s, __shfl_xor(s, 16));
        mp = fmaxf(mp, __shfl_xor(mp, 32));
        const float m_new = fmaxf(m_run, mp);
        const float alpha = fexp2(m_run - m_new);
        const float p = act ? fexp2(s - m_new) : 0.f;
        float ps = p + __shfl_xor(p, 16);
        ps += __shfl_xor(ps, 32);
        l_run = l_run * alpha + ps;
        oa.x = oa.x * alpha + p * b2f(vq.x);
        oa.y = oa.y * alpha + p * b2f(vq.y);
        oa.z = oa.z * alpha + p * b2f(vq.z);
        oa.w = oa.w * alpha + p * b2f(vq.w);
        m_run = m_new;
    }
    // reduce O across the 4 groups (lanes with same t)
#pragma unroll
    for (int d = 16; d <= 32; d <<= 1) {
        oa.x += __shfl_xor(oa.x, d);
        oa.y += __shfl_xor(oa.y, d);
        oa.z += __shfl_xor(oa.z, d);
        oa.w += __shfl_xor(oa.w, d);
    }
    if (g == 0) {
        const float rl = 1.f / l_run;
        ushort4 ov;
        ov.x = f2b(oa.x * rl);
        ov.y = f2b(oa.y * rl);
        ov.z = f2b(oa.z * rl);
        ov.w = f2b(oa.w * rl);
        *reinterpret_cast<ushort4*>(o_buf + (size_t)q * DD + h * DHH + t * 4) = ov;
    }
}

// ---------------- launch ----------------
extern "C" void kernel_launch(void* const* d_in, const int* in_sizes, int n_in,
                              void* d_out, int out_size, void* d_ws, size_t ws_size,
                              hipStream_t stream) {
    const float* x = (const float*)d_in[0];
    const void* ei = d_in[1];
    const float* ln1w = (const float*)d_in[2];
    const float* ln1b = (const float*)d_in[3];
    const float* w_in = (const float*)d_in[4];
    const float* b_in = (const float*)d_in[5];
    const float* w_out = (const float*)d_in[6];
    const float* b_out = (const float*)d_in[7];
    const float* ln2w = (const float*)d_in[8];
    const float* ln2b = (const float*)d_in[9];
    const float* w1 = (const float*)d_in[10];
    const float* b1 = (const float*)d_in[11];
    const float* w2 = (const float*)d_in[12];
    const float* b2 = (const float*)d_in[13];
    float* out = (float*)d_out;
    const int E = in_sizes[1] / 2;

    char* ws = (char*)d_ws;
    size_t off = 0;
    auto alloc = [&](size_t bytes) -> void* {
        void* p = ws + off;
        off = (off + bytes + 255) & ~(size_t)255;
        return p;
    };
    uint32* mask1 = (uint32*)alloc((size_t)NN * 128 * 4);
    uint32* mask2 = (uint32*)alloc((size_t)NN * 128 * 4);
    uint32* counts = (uint32*)alloc((size_t)NN * 4);
    uint32* starts = (uint32*)alloc((size_t)NN * 4);
    uint32* cursor = (uint32*)alloc((size_t)NN * 4);
    int* flag = (int*)alloc(256);
    int* cols = (int*)alloc((size_t)(E + NN) * 4);
    unsigned short* w_in_b = (unsigned short*)alloc((size_t)1536 * 512 * 2);
    unsigned short* w_out_b = (unsigned short*)alloc((size_t)512 * 512 * 2);
    unsigned short* w1_b = (unsigned short*)alloc((size_t)2048 * 512 * 2);
    unsigned short* w2_b = (unsigned short*)alloc((size_t)512 * 2048 * 2);
    unsigned short* xn = (unsigned short*)alloc((size_t)NN * DD * 2);
    float* q_f = (float*)alloc((size_t)NN * DD * 4);                 // 8 MiB
    unsigned short* k_b = (unsigned short*)alloc((size_t)NN * DD * 2); // 4 MiB
    unsigned short* v_b = (unsigned short*)alloc((size_t)NN * DD * 2); // 4 MiB
    unsigned short* o_buf = (unsigned short*)alloc((size_t)NN * DD * 2);
    float* x1 = (float*)alloc((size_t)NN * DD * 4);
    unsigned short* xm = (unsigned short*)alloc((size_t)NN * DD * 2);
    // MLP hidden [4096][2048] bf16 (16 MiB) aliases q_f+k_b+v_b (dead after attn)
    unsigned short* h_buf = (unsigned short*)q_f;

    hipMemsetAsync(mask1, 0, (size_t)NN * 128 * 4, stream);
    hipMemsetAsync(mask2, 0, (size_t)NN * 128 * 4, stream);
    hipMemsetAsync(counts, 0, (size_t)NN * 4, stream);

    cvt_bf16<<<(1536 * 512 + 255) / 256, 256, 0, stream>>>(w_in, w_in_b, 1536 * 512);
    cvt_bf16<<<(512 * 512 + 255) / 256, 256, 0, stream>>>(w_out, w_out_b, 512 * 512);
    cvt_bf16<<<(2048 * 512 + 255) / 256, 256, 0, stream>>>(w1, w1_b, 2048 * 512);
    cvt_bf16<<<(512 * 2048 + 255) / 256, 256, 0, stream>>>(w2, w2_b, 512 * 2048);

    detect_i32<<<1, 256, 0, stream>>>((const int*)ei, flag);

    const int tot = E + NN;
    adj_count<<<(tot + 255) / 256, 256, 0, stream>>>(ei, flag, mask1, counts, E);
    ln_rows<<<NN, 256, 0, stream>>>(x, ln1w, ln1b, xn);
    scan_rows<<<1, 1024, 0, stream>>>(counts, starts, cursor);
    adj_fill<<<(tot + 255) / 256, 256, 0, stream>>>(ei, flag, mask2, cursor, cols, E);

    // QKV: [4096,512] @ [1536,512]^T
    gemm_bt<0><<<dim3(12, 32), 256, 0, stream>>>(xn, w_in_b, 512, b_in, nullptr,
                                                 nullptr, nullptr, q_f, k_b, v_b);
    attn_sparse<<<NN * HH / 4, 256, 0, stream>>>(q_f, k_b, v_b, cols, starts, counts, o_buf);
    // attn_out + residual: x1 = x + o @ w_out^T + b_out
    gemm_bt<1><<<dim3(4, 32), 256, 0, stream>>>(o_buf, w_out_b, 512, b_out, x, x1,
                                                nullptr, nullptr, nullptr, nullptr);
    ln_rows<<<NN, 256, 0, stream>>>(x1, ln2w, ln2b, xm);
    // MLP1: relu(xm @ w1^T + b1) -> h (bf16)
    gemm_bt<2><<<dim3(16, 32), 256, 0, stream>>>(xm, w1_b, 512, b1, nullptr, nullptr,
                                                 h_buf, nullptr, nullptr, nullptr);
    // MLP2: out = x1 + h @ w2^T + b2
    gemm_bt<3><<<dim3(4, 32), 256, 0, stream>>>(h_buf, w2_b, 2048, b2, x1, out,
                                                nullptr, nullptr, nullptr, nullptr);
}

// Round 3
// 193.284 us; speedup vs baseline: 1.4613x; 1.0846x over previous
//
#include <hip/hip_runtime.h>

#define NN 4096
#define DD 512
#define HH 8
#define DHH 64

typedef __attribute__((ext_vector_type(8))) __bf16 bfrag;
typedef __attribute__((ext_vector_type(8))) short short8;
typedef __attribute__((ext_vector_type(8))) unsigned short ushort8v;
typedef __attribute__((ext_vector_type(4))) float f32x4;
typedef unsigned int uint32;

// f32 -> bf16 round-to-nearest-even
__device__ __forceinline__ unsigned short f2b(float f) {
    unsigned int u = __builtin_bit_cast(unsigned int, f);
    unsigned int r = 0x7fffu + ((u >> 16) & 1u);
    return (unsigned short)((u + r) >> 16);
}

__device__ __forceinline__ float b2f(unsigned short u) {
    return __builtin_bit_cast(float, (unsigned int)u << 16);
}

__device__ __forceinline__ float fexp2(float x) {
#if __has_builtin(__builtin_amdgcn_exp2f)
    return __builtin_amdgcn_exp2f(x);
#else
    return exp2f(x);
#endif
}

// ---------------- fused weight convert (all 4 weight matrices) ----------------
#define W_IN_N 786432
#define W_OUT_N 262144
#define W1_N 1048576
#define W2_N 1048576
__global__ __launch_bounds__(256) void cvt_all(const float* __restrict__ w_in,
                                               const float* __restrict__ w_out,
                                               const float* __restrict__ w1,
                                               const float* __restrict__ w2,
                                               unsigned short* __restrict__ o_in,
                                               unsigned short* __restrict__ o_out,
                                               unsigned short* __restrict__ o1,
                                               unsigned short* __restrict__ o2) {
    int idx = (blockIdx.x * 256 + threadIdx.x) * 4;
    const float* src;
    unsigned short* dst;
    int off;
    if (idx < W_IN_N) { src = w_in; dst = o_in; off = idx; }
    else if (idx < W_IN_N + W_OUT_N) { src = w_out; dst = o_out; off = idx - W_IN_N; }
    else if (idx < W_IN_N + W_OUT_N + W1_N) { src = w1; dst = o1; off = idx - (W_IN_N + W_OUT_N); }
    else { src = w2; dst = o2; off = idx - (W_IN_N + W_OUT_N + W1_N); }
    float4 v = *reinterpret_cast<const float4*>(src + off);
    ushort4 o;
    o.x = f2b(v.x); o.y = f2b(v.y); o.z = f2b(v.z); o.w = f2b(v.w);
    *reinterpret_cast<ushort4*>(dst + off) = o;
}

// ---------------- edge dtype detect (int64 vs int32) ----------------
__global__ void detect_i32(const int* __restrict__ ei32, int* __restrict__ flag) {
    __shared__ int any;
    if (threadIdx.x == 0) any = 0;
    __syncthreads();
    for (int i = threadIdx.x; i < 1024; i += 256)
        if (ei32[2 * i + 1] != 0) atomicOr(&any, 1);
    __syncthreads();
    if (threadIdx.x == 0) *flag = any;  // 1 -> int32 format, 0 -> int64
}

__device__ __forceinline__ void load_edge(const void* ei, int E, int i, int is32,
                                          int& r, int& c) {
    if (is32) {
        const int* p = (const int*)ei;
        r = p[i]; c = p[E + i];
    } else {
        const long long* p = (const long long*)ei;
        r = (int)p[i]; c = (int)p[E + i];
    }
}

// ---------------- adjacency build (deduped CSR) ----------------
__global__ __launch_bounds__(256) void adj_count(const void* __restrict__ ei,
                                                 const int* __restrict__ flag,
                                                 uint32* __restrict__ mask,
                                                 uint32* __restrict__ counts, int E) {
    int tid = blockIdx.x * 256 + threadIdx.x;
    int total = E + NN;
    if (tid >= total) return;
    int is32 = *flag;
    int r, c;
    if (tid < E) load_edge(ei, E, tid, is32, r, c);
    else { r = tid - E; c = r; }
    uint32 bit = 1u << (c & 31);
    uint32 old = atomicOr(&mask[r * 128 + (c >> 5)], bit);
    if (!(old & bit)) atomicAdd(&counts[r], 1u);
}

__global__ __launch_bounds__(256) void adj_fill(const void* __restrict__ ei,
                                                const int* __restrict__ flag,
                                                uint32* __restrict__ mask2,
                                                uint32* __restrict__ cursor,
                                                int* __restrict__ cols, int E) {
    int tid = blockIdx.x * 256 + threadIdx.x;
    int total = E + NN;
    if (tid >= total) return;
    int is32 = *flag;
    int r, c;
    if (tid < E) load_edge(ei, E, tid, is32, r, c);
    else { r = tid - E; c = r; }
    uint32 bit = 1u << (c & 31);
    uint32 old = atomicOr(&mask2[r * 128 + (c >> 5)], bit);
    if (!(old & bit)) {
        uint32 pos = atomicAdd(&cursor[r], 1u);
        cols[pos] = c;
    }
}

// exclusive scan over 4096 counts
__global__ __launch_bounds__(1024) void scan_rows(const uint32* __restrict__ counts,
                                                  uint32* __restrict__ starts,
                                                  uint32* __restrict__ cursor) {
    __shared__ uint32 tsum[1024];
    int tid = threadIdx.x;
    uint32 c0 = counts[tid * 4], c1 = counts[tid * 4 + 1];
    uint32 c2 = counts[tid * 4 + 2], c3 = counts[tid * 4 + 3];
    tsum[tid] = c0 + c1 + c2 + c3;
    __syncthreads();
    for (int d = 1; d < 1024; d <<= 1) {
        uint32 add = (tid >= d) ? tsum[tid - d] : 0u;
        __syncthreads();
        tsum[tid] += add;
        __syncthreads();
    }
    uint32 base = (tid > 0) ? tsum[tid - 1] : 0u;
    uint32 s0 = base, s1 = base + c0, s2 = s1 + c1, s3 = s2 + c2;
    starts[tid * 4] = s0; starts[tid * 4 + 1] = s1;
    starts[tid * 4 + 2] = s2; starts[tid * 4 + 3] = s3;
    cursor[tid * 4] = s0; cursor[tid * 4 + 1] = s1;
    cursor[tid * 4 + 2] = s2; cursor[tid * 4 + 3] = s3;
}

// ---------------- layernorm: f32 row -> bf16 row ----------------
__global__ __launch_bounds__(256) void ln_rows(const float* __restrict__ x,
                                               const float* __restrict__ w,
                                               const float* __restrict__ b,
                                               unsigned short* __restrict__ out) {
    const int row = blockIdx.x;
    const int tid = threadIdx.x;
    float2 v = reinterpret_cast<const float2*>(x + (size_t)row * DD)[tid];
    float s = v.x + v.y;
    float s2 = v.x * v.x + v.y * v.y;
#pragma unroll
    for (int d = 1; d < 64; d <<= 1) {
        s += __shfl_xor(s, d);
        s2 += __shfl_xor(s2, d);
    }
    __shared__ float red[8];
    if ((tid & 63) == 0) { red[tid >> 6] = s; red[4 + (tid >> 6)] = s2; }
    __syncthreads();
    s = red[0] + red[1] + red[2] + red[3];
    s2 = red[4] + red[5] + red[6] + red[7];
    const float mean = s * (1.f / DD);
    const float var = fmaxf(s2 * (1.f / DD) - mean * mean, 0.f);
    const float rs = rsqrtf(var + 1e-5f);
    const int c = tid * 2;
    out[(size_t)row * DD + c]     = f2b((v.x - mean) * rs * w[c] + b[c]);
    out[(size_t)row * DD + c + 1] = f2b((v.y - mean) * rs * w[c + 1] + b[c + 1]);
}

// ---------------- bf16 MFMA GEMM 128x128: C[M][N] = A @ B^T ----------------
// EPI 0: QKV -> q (f32, scaled), k/v (bf16) as [H][N][64]
// EPI 2: out_b[gr*2048+gc] = bf16(relu(acc + bias))
template <int EPI>
__global__ __launch_bounds__(256) void gemm_bt(const unsigned short* __restrict__ A,
                                               const unsigned short* __restrict__ B,
                                               int K,
                                               const float* __restrict__ bias,
                                               unsigned short* __restrict__ out_b,
                                               float* __restrict__ q_out,
                                               unsigned short* __restrict__ k_out,
                                               unsigned short* __restrict__ v_out) {
    __shared__ __align__(16) unsigned short a_lds[128 * 72];
    __shared__ __align__(16) unsigned short b_lds[128 * 72];
    const int tid = threadIdx.x;
    const int lane = tid & 63;
    const int wave = tid >> 6;
    const int wm = wave >> 1, wn = wave & 1;
    const int tm = blockIdx.y, tn = blockIdx.x;

    f32x4 acc[4][4];
#pragma unroll
    for (int mi = 0; mi < 4; ++mi)
#pragma unroll
        for (int ni = 0; ni < 4; ++ni) acc[mi][ni] = (f32x4){0.f, 0.f, 0.f, 0.f};

    const size_t a_base = (size_t)(tm * 128) * K;
    const size_t b_base = (size_t)(tn * 128) * K;

    for (int k0 = 0; k0 < K; k0 += 64) {
        __syncthreads();
#pragma unroll
        for (int it = 0; it < 4; ++it) {
            int slot = tid + 256 * it;
            int row = slot >> 3;
            int cs = (slot & 7) << 3;
            short8 va = *reinterpret_cast<const short8*>(A + a_base + (size_t)row * K + k0 + cs);
            short8 vb = *reinterpret_cast<const short8*>(B + b_base + (size_t)row * K + k0 + cs);
            *reinterpret_cast<short8*>(&a_lds[row * 72 + cs]) = va;
            *reinterpret_cast<short8*>(&b_lds[row * 72 + cs]) = vb;
        }
        __syncthreads();
#pragma unroll
        for (int ks = 0; ks < 2; ++ks) {
            const int kc = ((lane >> 4) << 3) + (ks << 5);
            bfrag af[4], bfr[4];
#pragma unroll
            for (int mi = 0; mi < 4; ++mi)
                af[mi] = *reinterpret_cast<const bfrag*>(
                    &a_lds[(wm * 64 + mi * 16 + (lane & 15)) * 72 + kc]);
#pragma unroll
            for (int ni = 0; ni < 4; ++ni)
                bfr[ni] = *reinterpret_cast<const bfrag*>(
                    &b_lds[(wn * 64 + ni * 16 + (lane & 15)) * 72 + kc]);
#pragma unroll
            for (int mi = 0; mi < 4; ++mi)
#pragma unroll
                for (int ni = 0; ni < 4; ++ni)
                    acc[mi][ni] = __builtin_amdgcn_mfma_f32_16x16x32_bf16(
                        af[mi], bfr[ni], acc[mi][ni], 0, 0, 0);
        }
    }

    const int r0 = (lane >> 4) << 2;
    const int cl = lane & 15;
#pragma unroll
    for (int mi = 0; mi < 4; ++mi) {
#pragma unroll
        for (int ni = 0; ni < 4; ++ni) {
#pragma unroll
            for (int r = 0; r < 4; ++r) {
                int gr = tm * 128 + wm * 64 + mi * 16 + r0 + r;
                int gc = tn * 128 + wn * 64 + ni * 16 + cl;
                float v = acc[mi][ni][r] + bias[gc];
                if (EPI == 0) {
                    if (gc < 512) {
                        q_out[((size_t)((gc >> 6) * NN) + gr) * 64 + (gc & 63)] =
                            v * 0.18033688011112042f;   // 1/sqrt(64) * log2(e)
                    } else if (gc < 1024) {
                        int j = gc - 512;
                        k_out[((size_t)((j >> 6) * NN) + gr) * 64 + (j & 63)] = f2b(v);
                    } else {
                        int j = gc - 1024;
                        v_out[((size_t)((j >> 6) * NN) + gr) * 64 + (j & 63)] = f2b(v);
                    }
                } else {
                    out_b[(size_t)gr * 2048 + gc] = f2b(fmaxf(v, 0.f));
                }
            }
        }
    }
}

// ---------------- bf16 MFMA GEMM 128x64: out = acc + bias + resid (N=512 out) --
__global__ __launch_bounds__(256) void gemm_bt64(const unsigned short* __restrict__ A,
                                                 const unsigned short* __restrict__ B,
                                                 int K,
                                                 const float* __restrict__ bias,
                                                 const float* __restrict__ resid,
                                                 float* __restrict__ out_f) {
    __shared__ __align__(16) unsigned short a_lds[128 * 72];
    __shared__ __align__(16) unsigned short b_lds[64 * 72];
    const int tid = threadIdx.x;
    const int lane = tid & 63;
    const int wave = tid >> 6;
    const int wm = wave >> 1, wn = wave & 1;
    const int tm = blockIdx.y, tn = blockIdx.x;

    f32x4 acc[4][2];
#pragma unroll
    for (int mi = 0; mi < 4; ++mi)
#pragma unroll
        for (int ni = 0; ni < 2; ++ni) acc[mi][ni] = (f32x4){0.f, 0.f, 0.f, 0.f};

    const size_t a_base = (size_t)(tm * 128) * K;
    const size_t b_base = (size_t)(tn * 64) * K;

    for (int k0 = 0; k0 < K; k0 += 64) {
        __syncthreads();
#pragma unroll
        for (int it = 0; it < 4; ++it) {
            int slot = tid + 256 * it;      // A: 128 rows x 8 chunks
            int row = slot >> 3;
            int cs = (slot & 7) << 3;
            *reinterpret_cast<short8*>(&a_lds[row * 72 + cs]) =
                *reinterpret_cast<const short8*>(A + a_base + (size_t)row * K + k0 + cs);
        }
#pragma unroll
        for (int it = 0; it < 2; ++it) {
            int slot = tid + 256 * it;      // B: 64 rows x 8 chunks
            int row = slot >> 3;
            int cs = (slot & 7) << 3;
            *reinterpret_cast<short8*>(&b_lds[row * 72 + cs]) =
                *reinterpret_cast<const short8*>(B + b_base + (size_t)row * K + k0 + cs);
        }
        __syncthreads();
#pragma unroll
        for (int ks = 0; ks < 2; ++ks) {
            const int kc = ((lane >> 4) << 3) + (ks << 5);
            bfrag af[4], bfr[2];
#pragma unroll
            for (int mi = 0; mi < 4; ++mi)
                af[mi] = *reinterpret_cast<const bfrag*>(
                    &a_lds[(wm * 64 + mi * 16 + (lane & 15)) * 72 + kc]);
#pragma unroll
            for (int ni = 0; ni < 2; ++ni)
                bfr[ni] = *reinterpret_cast<const bfrag*>(
                    &b_lds[(wn * 32 + ni * 16 + (lane & 15)) * 72 + kc]);
#pragma unroll
            for (int mi = 0; mi < 4; ++mi)
#pragma unroll
                for (int ni = 0; ni < 2; ++ni)
                    acc[mi][ni] = __builtin_amdgcn_mfma_f32_16x16x32_bf16(
                        af[mi], bfr[ni], acc[mi][ni], 0, 0, 0);
        }
    }

    const int r0 = (lane >> 4) << 2;
    const int cl = lane & 15;
#pragma unroll
    for (int mi = 0; mi < 4; ++mi) {
#pragma unroll
        for (int ni = 0; ni < 2; ++ni) {
#pragma unroll
            for (int r = 0; r < 4; ++r) {
                int gr = tm * 128 + wm * 64 + mi * 16 + r0 + r;
                int gc = tn * 64 + wn * 32 + ni * 16 + cl;
                out_f[(size_t)gr * 512 + gc] =
                    acc[mi][ni][r] + bias[gc] + resid[(size_t)gr * 512 + gc];
            }
        }
    }
}

// ---------------- sparse masked attention: two-pass, scores in registers ------
// wave per (head, query). 8 groups x 8 lanes; group g handles neighbor p0+g,
// lane t covers dims [8t, 8t+8). Chunk of <=64 neighbors: pass 1 computes all
// scores into statically-indexed registers (only fmax crosses iterations),
// pass 2 does exp2 + PV with zero shuffles in the loop.
__global__ __launch_bounds__(256) void attn_sparse(const float* __restrict__ qf,
                                                   const unsigned short* __restrict__ kb,
                                                   const unsigned short* __restrict__ vb,
                                                   const int* __restrict__ cols,
                                                   const uint32* __restrict__ starts,
                                                   const uint32* __restrict__ counts,
                                                   unsigned short* __restrict__ o_buf) {
    const int lane = threadIdx.x & 63;
    const int wid = threadIdx.x >> 6;
    const int gw = blockIdx.x * 4 + wid;
    const int h = gw >> 12;         // / 4096
    const int q = gw & (NN - 1);
    const int g = lane >> 3;        // neighbor group 0..7
    const int t = lane & 7;         // dim slot: dims [8t, 8t+8)

    const float4* qp = reinterpret_cast<const float4*>(
        qf + ((size_t)h * NN + q) * DHH + t * 8);
    const float4 q0 = qp[0], q1 = qp[1];

    const int cnt = (int)counts[q];
    const int base = (int)starts[q];
    const unsigned short* kh = kb + (size_t)h * NN * DHH;
    const unsigned short* vh = vb + (size_t)h * NN * DHH;

    float m_run = -3.0e38f, l_run = 0.f;
    float oa[8];
#pragma unroll
    for (int i = 0; i < 8; ++i) oa[i] = 0.f;

    for (int c0 = 0; c0 < cnt; c0 += 64) {
        const int clen = min(64, cnt - c0);
        float s_arr[8];
        int col_arr[8];
        float mloc = -3.0e38f;
        // ---- pass 1: scores ----
#pragma unroll
        for (int u = 0; u < 8; ++u) {
            const int p0 = u * 8;
            float s = -3.0e38f;
            int col = 0;
            if (p0 < clen) {                       // wave-uniform
                const int jj = p0 + g;
                const bool act = jj < clen;
                col = act ? cols[base + c0 + jj] : 0;
                ushort8v kq = *reinterpret_cast<const ushort8v*>(
                    kh + (size_t)col * DHH + t * 8);
                float d = q0.x * b2f(kq[0]);
                d = fmaf(q0.y, b2f(kq[1]), d);
                d = fmaf(q0.z, b2f(kq[2]), d);
                d = fmaf(q0.w, b2f(kq[3]), d);
                d = fmaf(q1.x, b2f(kq[4]), d);
                d = fmaf(q1.y, b2f(kq[5]), d);
                d = fmaf(q1.z, b2f(kq[6]), d);
                d = fmaf(q1.w, b2f(kq[7]), d);
                d += __shfl_xor(d, 1);
                d += __shfl_xor(d, 2);
                d += __shfl_xor(d, 4);
                s = act ? d : -3.0e38f;
            }
            s_arr[u] = s;
            col_arr[u] = col;
            mloc = fmaxf(mloc, s);
        }
        // max across the 8 groups
        mloc = fmaxf(mloc, __shfl_xor(mloc, 8));
        mloc = fmaxf(mloc, __shfl_xor(mloc, 16));
        mloc = fmaxf(mloc, __shfl_xor(mloc, 32));
        const float m_new = fmaxf(m_run, mloc);
        const float alpha = fexp2(m_run - m_new);  // chunk 0: exp2(-huge) = 0
        l_run *= alpha;
#pragma unroll
        for (int i = 0; i < 8; ++i) oa[i] *= alpha;
        m_run = m_new;
        // ---- pass 2: exp + PV (no shuffles) ----
#pragma unroll
        for (int u = 0; u < 8; ++u) {
            const int p0 = u * 8;
            if (p0 < clen) {
                const float p = fexp2(s_arr[u] - m_run);  // inactive: exp2(-huge)=0
                l_run += p;
                ushort8v vq = *reinterpret_cast<const ushort8v*>(
                    vh + (size_t)col_arr[u] * DHH + t * 8);
#pragma unroll
                for (int i = 0; i < 8; ++i) oa[i] = fmaf(p, b2f(vq[i]), oa[i]);
            }
        }
    }
    // reduce l and O across the 8 groups (butterfly -> all lanes hold sums)
    l_run += __shfl_xor(l_run, 8);
    l_run += __shfl_xor(l_run, 16);
    l_run += __shfl_xor(l_run, 32);
#pragma unroll
    for (int d = 8; d <= 32; d <<= 1)
#pragma unroll
        for (int i = 0; i < 8; ++i) oa[i] += __shfl_xor(oa[i], d);

    if (g == 0) {
        const float rl = 1.f / l_run;
        ushort8v ov;
#pragma unroll
        for (int i = 0; i < 8; ++i) ov[i] = f2b(oa[i] * rl);
        *reinterpret_cast<ushort8v*>(o_buf + (size_t)q * DD + h * DHH + t * 8) = ov;
    }
}

// ---------------- launch ----------------
extern "C" void kernel_launch(void* const* d_in, const int* in_sizes, int n_in,
                              void* d_out, int out_size, void* d_ws, size_t ws_size,
                              hipStream_t stream) {
    const float* x = (const float*)d_in[0];
    const void* ei = d_in[1];
    const float* ln1w = (const float*)d_in[2];
    const float* ln1b = (const float*)d_in[3];
    const float* w_in = (const float*)d_in[4];
    const float* b_in = (const float*)d_in[5];
    const float* w_out = (const float*)d_in[6];
    const float* b_out = (const float*)d_in[7];
    const float* ln2w = (const float*)d_in[8];
    const float* ln2b = (const float*)d_in[9];
    const float* w1 = (const float*)d_in[10];
    const float* b1 = (const float*)d_in[11];
    const float* w2 = (const float*)d_in[12];
    const float* b2 = (const float*)d_in[13];
    float* out = (float*)d_out;
    const int E = in_sizes[1] / 2;

    char* ws = (char*)d_ws;
    size_t off = 0;
    auto alloc = [&](size_t bytes) -> void* {
        void* p = ws + off;
        off = (off + bytes + 255) & ~(size_t)255;
        return p;
    };
    uint32* mask1 = (uint32*)alloc((size_t)NN * 128 * 4);
    uint32* mask2 = (uint32*)alloc((size_t)NN * 128 * 4);
    uint32* counts = (uint32*)alloc((size_t)NN * 4);
    uint32* starts = (uint32*)alloc((size_t)NN * 4);
    uint32* cursor = (uint32*)alloc((size_t)NN * 4);
    int* flag = (int*)alloc(256);
    int* cols = (int*)alloc((size_t)(E + NN) * 4);
    unsigned short* w_in_b = (unsigned short*)alloc((size_t)1536 * 512 * 2);
    unsigned short* w_out_b = (unsigned short*)alloc((size_t)512 * 512 * 2);
    unsigned short* w1_b = (unsigned short*)alloc((size_t)2048 * 512 * 2);
    unsigned short* w2_b = (unsigned short*)alloc((size_t)512 * 2048 * 2);
    unsigned short* xn = (unsigned short*)alloc((size_t)NN * DD * 2);
    float* q_f = (float*)alloc((size_t)NN * DD * 4);                   // 8 MiB
    unsigned short* k_b = (unsigned short*)alloc((size_t)NN * DD * 2); // 4 MiB
    unsigned short* v_b = (unsigned short*)alloc((size_t)NN * DD * 2); // 4 MiB
    unsigned short* o_buf = (unsigned short*)alloc((size_t)NN * DD * 2);
    float* x1 = (float*)alloc((size_t)NN * DD * 4);
    unsigned short* xm = (unsigned short*)alloc((size_t)NN * DD * 2);
    // MLP hidden [4096][2048] bf16 (16 MiB) aliases q_f+k_b+v_b (dead after attn)
    unsigned short* h_buf = (unsigned short*)q_f;

    hipMemsetAsync(mask1, 0, (size_t)NN * 128 * 4, stream);
    hipMemsetAsync(mask2, 0, (size_t)NN * 128 * 4, stream);
    hipMemsetAsync(counts, 0, (size_t)NN * 4, stream);

    cvt_all<<<(W_IN_N + W_OUT_N + W1_N + W2_N) / 4 / 256, 256, 0, stream>>>(
        w_in, w_out, w1, w2, w_in_b, w_out_b, w1_b, w2_b);

    detect_i32<<<1, 256, 0, stream>>>((const int*)ei, flag);

    const int tot = E + NN;
    adj_count<<<(tot + 255) / 256, 256, 0, stream>>>(ei, flag, mask1, counts, E);
    ln_rows<<<NN, 256, 0, stream>>>(x, ln1w, ln1b, xn);
    scan_rows<<<1, 1024, 0, stream>>>(counts, starts, cursor);
    adj_fill<<<(tot + 255) / 256, 256, 0, stream>>>(ei, flag, mask2, cursor, cols, E);

    // QKV: [4096,512] @ [1536,512]^T
    gemm_bt<0><<<dim3(12, 32), 256, 0, stream>>>(xn, w_in_b, 512, b_in,
                                                 nullptr, q_f, k_b, v_b);
    attn_sparse<<<NN * HH / 4, 256, 0, stream>>>(q_f, k_b, v_b, cols, starts, counts, o_buf);
    // attn_out + residual: x1 = x + o @ w_out^T + b_out   (256 WGs)
    gemm_bt64<<<dim3(8, 32), 256, 0, stream>>>(o_buf, w_out_b, 512, b_out, x, x1);
    ln_rows<<<NN, 256, 0, stream>>>(x1, ln2w, ln2b, xm);
    // MLP1: relu(xm @ w1^T + b1) -> h (bf16)
    gemm_bt<2><<<dim3(16, 32), 256, 0, stream>>>(xm, w1_b, 512, b1,
                                                 h_buf, nullptr, nullptr, nullptr);
    // MLP2: out = x1 + h @ w2^T + b2   (256 WGs)
    gemm_bt64<<<dim3(8, 32), 256, 0, stream>>>(h_buf, w2_b, 2048, b2, x1, out);
}

// Round 4
// 173.604 us; speedup vs baseline: 1.6269x; 1.1134x over previous
//
#include <hip/hip_runtime.h>

#define NN 4096
#define DD 512
#define HH 8
#define DHH 64

typedef __attribute__((ext_vector_type(8))) __bf16 bfrag;
typedef __attribute__((ext_vector_type(8))) short short8;
typedef __attribute__((ext_vector_type(8))) unsigned short ushort8v;
typedef __attribute__((ext_vector_type(4))) float f32x4;
typedef unsigned int uint32;

// f32 -> bf16 round-to-nearest-even
__device__ __forceinline__ unsigned short f2b(float f) {
    unsigned int u = __builtin_bit_cast(unsigned int, f);
    unsigned int r = 0x7fffu + ((u >> 16) & 1u);
    return (unsigned short)((u + r) >> 16);
}

__device__ __forceinline__ float b2f(unsigned short u) {
    return __builtin_bit_cast(float, (unsigned int)u << 16);
}

__device__ __forceinline__ float fexp2(float x) {
#if __has_builtin(__builtin_amdgcn_exp2f)
    return __builtin_amdgcn_exp2f(x);
#else
    return exp2f(x);
#endif
}

// ---------------- fused weight convert (all 4 weight matrices) ----------------
#define W_IN_N 786432
#define W_OUT_N 262144
#define W1_N 1048576
#define W2_N 1048576
__global__ __launch_bounds__(256) void cvt_all(const float* __restrict__ w_in,
                                               const float* __restrict__ w_out,
                                               const float* __restrict__ w1,
                                               const float* __restrict__ w2,
                                               unsigned short* __restrict__ o_in,
                                               unsigned short* __restrict__ o_out,
                                               unsigned short* __restrict__ o1,
                                               unsigned short* __restrict__ o2) {
    int idx = (blockIdx.x * 256 + threadIdx.x) * 4;
    const float* src;
    unsigned short* dst;
    int off;
    if (idx < W_IN_N) { src = w_in; dst = o_in; off = idx; }
    else if (idx < W_IN_N + W_OUT_N) { src = w_out; dst = o_out; off = idx - W_IN_N; }
    else if (idx < W_IN_N + W_OUT_N + W1_N) { src = w1; dst = o1; off = idx - (W_IN_N + W_OUT_N); }
    else { src = w2; dst = o2; off = idx - (W_IN_N + W_OUT_N + W1_N); }
    float4 v = *reinterpret_cast<const float4*>(src + off);
    ushort4 o;
    o.x = f2b(v.x); o.y = f2b(v.y); o.z = f2b(v.z); o.w = f2b(v.w);
    *reinterpret_cast<ushort4*>(dst + off) = o;
}

// ---------------- edge dtype detect (int64 vs int32) ----------------
__global__ void detect_i32(const int* __restrict__ ei32, int* __restrict__ flag) {
    __shared__ int any;
    if (threadIdx.x == 0) any = 0;
    __syncthreads();
    for (int i = threadIdx.x; i < 1024; i += 256)
        if (ei32[2 * i + 1] != 0) atomicOr(&any, 1);
    __syncthreads();
    if (threadIdx.x == 0) *flag = any;  // 1 -> int32 format, 0 -> int64
}

__device__ __forceinline__ void load_edge(const void* ei, int E, int i, int is32,
                                          int& r, int& c) {
    if (is32) {
        const int* p = (const int*)ei;
        r = p[i]; c = p[E + i];
    } else {
        const long long* p = (const long long*)ei;
        r = (int)p[i]; c = (int)p[E + i];
    }
}

// ---------------- adjacency build (deduped CSR) ----------------
__global__ __launch_bounds__(256) void adj_count(const void* __restrict__ ei,
                                                 const int* __restrict__ flag,
                                                 uint32* __restrict__ mask,
                                                 uint32* __restrict__ counts, int E) {
    int tid = blockIdx.x * 256 + threadIdx.x;
    int total = E + NN;
    if (tid >= total) return;
    int is32 = *flag;
    int r, c;
    if (tid < E) load_edge(ei, E, tid, is32, r, c);
    else { r = tid - E; c = r; }
    uint32 bit = 1u << (c & 31);
    uint32 old = atomicOr(&mask[r * 128 + (c >> 5)], bit);
    if (!(old & bit)) atomicAdd(&counts[r], 1u);
}

__global__ __launch_bounds__(256) void adj_fill(const void* __restrict__ ei,
                                                const int* __restrict__ flag,
                                                uint32* __restrict__ mask2,
                                                uint32* __restrict__ cursor,
                                                int* __restrict__ cols, int E) {
    int tid = blockIdx.x * 256 + threadIdx.x;
    int total = E + NN;
    if (tid >= total) return;
    int is32 = *flag;
    int r, c;
    if (tid < E) load_edge(ei, E, tid, is32, r, c);
    else { r = tid - E; c = r; }
    uint32 bit = 1u << (c & 31);
    uint32 old = atomicOr(&mask2[r * 128 + (c >> 5)], bit);
    if (!(old & bit)) {
        uint32 pos = atomicAdd(&cursor[r], 1u);
        cols[pos] = c;
    }
}

// exclusive scan over 4096 counts
__global__ __launch_bounds__(1024) void scan_rows(const uint32* __restrict__ counts,
                                                  uint32* __restrict__ starts,
                                                  uint32* __restrict__ cursor) {
    __shared__ uint32 tsum[1024];
    int tid = threadIdx.x;
    uint32 c0 = counts[tid * 4], c1 = counts[tid * 4 + 1];
    uint32 c2 = counts[tid * 4 + 2], c3 = counts[tid * 4 + 3];
    tsum[tid] = c0 + c1 + c2 + c3;
    __syncthreads();
    for (int d = 1; d < 1024; d <<= 1) {
        uint32 add = (tid >= d) ? tsum[tid - d] : 0u;
        __syncthreads();
        tsum[tid] += add;
        __syncthreads();
    }
    uint32 base = (tid > 0) ? tsum[tid - 1] : 0u;
    uint32 s0 = base, s1 = base + c0, s2 = s1 + c1, s3 = s2 + c2;
    starts[tid * 4] = s0; starts[tid * 4 + 1] = s1;
    starts[tid * 4 + 2] = s2; starts[tid * 4 + 3] = s3;
    cursor[tid * 4] = s0; cursor[tid * 4 + 1] = s1;
    cursor[tid * 4 + 2] = s2; cursor[tid * 4 + 3] = s3;
}

// ---------------- layernorm: f32 row -> bf16 row ----------------
__global__ __launch_bounds__(256) void ln_rows(const float* __restrict__ x,
                                               const float* __restrict__ w,
                                               const float* __restrict__ b,
                                               unsigned short* __restrict__ out) {
    const int row = blockIdx.x;
    const int tid = threadIdx.x;
    float2 v = reinterpret_cast<const float2*>(x + (size_t)row * DD)[tid];
    float s = v.x + v.y;
    float s2 = v.x * v.x + v.y * v.y;
#pragma unroll
    for (int d = 1; d < 64; d <<= 1) {
        s += __shfl_xor(s, d);
        s2 += __shfl_xor(s2, d);
    }
    __shared__ float red[8];
    if ((tid & 63) == 0) { red[tid >> 6] = s; red[4 + (tid >> 6)] = s2; }
    __syncthreads();
    s = red[0] + red[1] + red[2] + red[3];
    s2 = red[4] + red[5] + red[6] + red[7];
    const float mean = s * (1.f / DD);
    const float var = fmaxf(s2 * (1.f / DD) - mean * mean, 0.f);
    const float rs = rsqrtf(var + 1e-5f);
    const int c = tid * 2;
    out[(size_t)row * DD + c]     = f2b((v.x - mean) * rs * w[c] + b[c]);
    out[(size_t)row * DD + c + 1] = f2b((v.y - mean) * rs * w[c + 1] + b[c + 1]);
}

// ---------------- bf16 MFMA GEMM 128x128: C[M][N] = A @ B^T ----------------
// EPI 0: QKV -> q (f32, scaled) [N][512], k/v (bf16) [N][512]
// EPI 2: out_b[gr*2048+gc] = bf16(relu(acc + bias))
template <int EPI>
__global__ __launch_bounds__(256) void gemm_bt(const unsigned short* __restrict__ A,
                                               const unsigned short* __restrict__ B,
                                               int K,
                                               const float* __restrict__ bias,
                                               unsigned short* __restrict__ out_b,
                                               float* __restrict__ q_out,
                                               unsigned short* __restrict__ k_out,
                                               unsigned short* __restrict__ v_out) {
    __shared__ __align__(16) unsigned short a_lds[128 * 72];
    __shared__ __align__(16) unsigned short b_lds[128 * 72];
    const int tid = threadIdx.x;
    const int lane = tid & 63;
    const int wave = tid >> 6;
    const int wm = wave >> 1, wn = wave & 1;
    const int tm = blockIdx.y, tn = blockIdx.x;

    f32x4 acc[4][4];
#pragma unroll
    for (int mi = 0; mi < 4; ++mi)
#pragma unroll
        for (int ni = 0; ni < 4; ++ni) acc[mi][ni] = (f32x4){0.f, 0.f, 0.f, 0.f};

    const size_t a_base = (size_t)(tm * 128) * K;
    const size_t b_base = (size_t)(tn * 128) * K;

    for (int k0 = 0; k0 < K; k0 += 64) {
        __syncthreads();
#pragma unroll
        for (int it = 0; it < 4; ++it) {
            int slot = tid + 256 * it;
            int row = slot >> 3;
            int cs = (slot & 7) << 3;
            short8 va = *reinterpret_cast<const short8*>(A + a_base + (size_t)row * K + k0 + cs);
            short8 vb = *reinterpret_cast<const short8*>(B + b_base + (size_t)row * K + k0 + cs);
            *reinterpret_cast<short8*>(&a_lds[row * 72 + cs]) = va;
            *reinterpret_cast<short8*>(&b_lds[row * 72 + cs]) = vb;
        }
        __syncthreads();
#pragma unroll
        for (int ks = 0; ks < 2; ++ks) {
            const int kc = ((lane >> 4) << 3) + (ks << 5);
            bfrag af[4], bfr[4];
#pragma unroll
            for (int mi = 0; mi < 4; ++mi)
                af[mi] = *reinterpret_cast<const bfrag*>(
                    &a_lds[(wm * 64 + mi * 16 + (lane & 15)) * 72 + kc]);
#pragma unroll
            for (int ni = 0; ni < 4; ++ni)
                bfr[ni] = *reinterpret_cast<const bfrag*>(
                    &b_lds[(wn * 64 + ni * 16 + (lane & 15)) * 72 + kc]);
#pragma unroll
            for (int mi = 0; mi < 4; ++mi)
#pragma unroll
                for (int ni = 0; ni < 4; ++ni)
                    acc[mi][ni] = __builtin_amdgcn_mfma_f32_16x16x32_bf16(
                        af[mi], bfr[ni], acc[mi][ni], 0, 0, 0);
        }
    }

    const int r0 = (lane >> 4) << 2;
    const int cl = lane & 15;
#pragma unroll
    for (int mi = 0; mi < 4; ++mi) {
#pragma unroll
        for (int ni = 0; ni < 4; ++ni) {
#pragma unroll
            for (int r = 0; r < 4; ++r) {
                int gr = tm * 128 + wm * 64 + mi * 16 + r0 + r;
                int gc = tn * 128 + wn * 64 + ni * 16 + cl;
                float v = acc[mi][ni][r] + bias[gc];
                if (EPI == 0) {
                    if (gc < 512) {
                        // fold score scale (1/sqrt(64)) and log2(e) into q
                        q_out[(size_t)gr * 512 + gc] = v * 0.18033688011112042f;
                    } else if (gc < 1024) {
                        k_out[(size_t)gr * 512 + (gc - 512)] = f2b(v);
                    } else {
                        v_out[(size_t)gr * 512 + (gc - 1024)] = f2b(v);
                    }
                } else {
                    out_b[(size_t)gr * 2048 + gc] = f2b(fmaxf(v, 0.f));
                }
            }
        }
    }
}

// ---------------- bf16 MFMA GEMM 128x64: out = acc + bias + resid (N=512 out) --
__global__ __launch_bounds__(256) void gemm_bt64(const unsigned short* __restrict__ A,
                                                 const unsigned short* __restrict__ B,
                                                 int K,
                                                 const float* __restrict__ bias,
                                                 const float* __restrict__ resid,
                                                 float* __restrict__ out_f) {
    __shared__ __align__(16) unsigned short a_lds[128 * 72];
    __shared__ __align__(16) unsigned short b_lds[64 * 72];
    const int tid = threadIdx.x;
    const int lane = tid & 63;
    const int wave = tid >> 6;
    const int wm = wave >> 1, wn = wave & 1;
    const int tm = blockIdx.y, tn = blockIdx.x;

    f32x4 acc[4][2];
#pragma unroll
    for (int mi = 0; mi < 4; ++mi)
#pragma unroll
        for (int ni = 0; ni < 2; ++ni) acc[mi][ni] = (f32x4){0.f, 0.f, 0.f, 0.f};

    const size_t a_base = (size_t)(tm * 128) * K;
    const size_t b_base = (size_t)(tn * 64) * K;

    for (int k0 = 0; k0 < K; k0 += 64) {
        __syncthreads();
#pragma unroll
        for (int it = 0; it < 4; ++it) {
            int slot = tid + 256 * it;      // A: 128 rows x 8 chunks
            int row = slot >> 3;
            int cs = (slot & 7) << 3;
            *reinterpret_cast<short8*>(&a_lds[row * 72 + cs]) =
                *reinterpret_cast<const short8*>(A + a_base + (size_t)row * K + k0 + cs);
        }
#pragma unroll
        for (int it = 0; it < 2; ++it) {
            int slot = tid + 256 * it;      // B: 64 rows x 8 chunks
            int row = slot >> 3;
            int cs = (slot & 7) << 3;
            *reinterpret_cast<short8*>(&b_lds[row * 72 + cs]) =
                *reinterpret_cast<const short8*>(B + b_base + (size_t)row * K + k0 + cs);
        }
        __syncthreads();
#pragma unroll
        for (int ks = 0; ks < 2; ++ks) {
            const int kc = ((lane >> 4) << 3) + (ks << 5);
            bfrag af[4], bfr[2];
#pragma unroll
            for (int mi = 0; mi < 4; ++mi)
                af[mi] = *reinterpret_cast<const bfrag*>(
                    &a_lds[(wm * 64 + mi * 16 + (lane & 15)) * 72 + kc]);
#pragma unroll
            for (int ni = 0; ni < 2; ++ni)
                bfr[ni] = *reinterpret_cast<const bfrag*>(
                    &b_lds[(wn * 32 + ni * 16 + (lane & 15)) * 72 + kc]);
#pragma unroll
            for (int mi = 0; mi < 4; ++mi)
#pragma unroll
                for (int ni = 0; ni < 2; ++ni)
                    acc[mi][ni] = __builtin_amdgcn_mfma_f32_16x16x32_bf16(
                        af[mi], bfr[ni], acc[mi][ni], 0, 0, 0);
        }
    }

    const int r0 = (lane >> 4) << 2;
    const int cl = lane & 15;
#pragma unroll
    for (int mi = 0; mi < 4; ++mi) {
#pragma unroll
        for (int ni = 0; ni < 2; ++ni) {
#pragma unroll
            for (int r = 0; r < 4; ++r) {
                int gr = tm * 128 + wm * 64 + mi * 16 + r0 + r;
                int gc = tn * 64 + wn * 32 + ni * 16 + cl;
                out_f[(size_t)gr * 512 + gc] =
                    acc[mi][ni][r] + bias[gc] + resid[(size_t)gr * 512 + gc];
            }
        }
    }
}

// ---------------- sparse masked attention: all 8 heads fused per wave --------
// wave per query. lane = (h, t): h = lane>>3 (head), t = lane&7 (dims 8t..8t+8).
// Per neighbor: ONE coalesced 1KB row load serves all heads (addr = col*1024 +
// lane*16, SGPR base via uniform readlane broadcast of col). Two-pass over
// bodies of 8 neighbors; scores live in statically-indexed registers; softmax
// state per head computed redundantly in-lane (no cross-group reductions); each
// lane exclusively owns output dims -> no O reduction, coalesced 1KB store.
__global__ __launch_bounds__(256) void attn_sparse(const float* __restrict__ qf,
                                                   const unsigned short* __restrict__ kb,
                                                   const unsigned short* __restrict__ vb,
                                                   const int* __restrict__ cols,
                                                   const uint32* __restrict__ starts,
                                                   const uint32* __restrict__ counts,
                                                   unsigned short* __restrict__ o_buf) {
    const int lane = threadIdx.x & 63;
    const int wid = threadIdx.x >> 6;
    const int q = blockIdx.x * 4 + wid;

    const float4* qp = reinterpret_cast<const float4*>(qf + (size_t)q * DD + lane * 8);
    const float4 q0 = qp[0], q1 = qp[1];

    const int cnt = (int)counts[q];
    const int base = (int)starts[q];

    float m_run = -3.0e38f, l_run = 0.f;
    float oa[8];
#pragma unroll
    for (int i = 0; i < 8; ++i) oa[i] = 0.f;

    for (int cc = 0; cc < cnt; cc += 64) {
        const int clen = min(64, cnt - cc);
        const int colv = (lane < clen) ? cols[base + cc + lane] : 0;

        for (int j0 = 0; j0 < clen; j0 += 8) {
            float s_arr[8];
            int col_arr[8];
            // ---- pass 1: scores for 8 neighbors (8 independent 1KB gathers) --
#pragma unroll
            for (int u = 0; u < 8; ++u) {
                const int col = __shfl(colv, j0 + u);   // uniform -> readlane
                col_arr[u] = col;
                const bool act = (j0 + u) < clen;
                ushort8v kq = *reinterpret_cast<const ushort8v*>(
                    kb + (size_t)col * DD + lane * 8);
                float d = q0.x * b2f(kq[0]);
                d = fmaf(q0.y, b2f(kq[1]), d);
                d = fmaf(q0.z, b2f(kq[2]), d);
                d = fmaf(q0.w, b2f(kq[3]), d);
                d = fmaf(q1.x, b2f(kq[4]), d);
                d = fmaf(q1.y, b2f(kq[5]), d);
                d = fmaf(q1.z, b2f(kq[6]), d);
                d = fmaf(q1.w, b2f(kq[7]), d);
                // reduce across the 8 lanes of this head
                d += __shfl_xor(d, 1);
                d += __shfl_xor(d, 2);
                d += __shfl_xor(d, 4);
                s_arr[u] = act ? d : -3.0e38f;
            }
            float mloc = fmaxf(fmaxf(fmaxf(s_arr[0], s_arr[1]), fmaxf(s_arr[2], s_arr[3])),
                               fmaxf(fmaxf(s_arr[4], s_arr[5]), fmaxf(s_arr[6], s_arr[7])));
            if (mloc > m_run) {                 // defer-rescale: alpha==1 otherwise
                const float alpha = fexp2(m_run - mloc);
                l_run *= alpha;
#pragma unroll
                for (int i = 0; i < 8; ++i) oa[i] *= alpha;
                m_run = mloc;
            }
            // ---- pass 2: exp + PV (no shuffles) ----
#pragma unroll
            for (int u = 0; u < 8; ++u) {
                const float p = fexp2(s_arr[u] - m_run);  // inactive -> 0
                l_run += p;
                ushort8v vq = *reinterpret_cast<const ushort8v*>(
                    vb + (size_t)col_arr[u] * DD + lane * 8);
#pragma unroll
                for (int i = 0; i < 8; ++i) oa[i] = fmaf(p, b2f(vq[i]), oa[i]);
            }
        }
    }

    const float rl = 1.f / l_run;
    ushort8v ov;
#pragma unroll
    for (int i = 0; i < 8; ++i) ov[i] = f2b(oa[i] * rl);
    *reinterpret_cast<ushort8v*>(o_buf + (size_t)q * DD + lane * 8) = ov;
}

// ---------------- launch ----------------
extern "C" void kernel_launch(void* const* d_in, const int* in_sizes, int n_in,
                              void* d_out, int out_size, void* d_ws, size_t ws_size,
                              hipStream_t stream) {
    const float* x = (const float*)d_in[0];
    const void* ei = d_in[1];
    const float* ln1w = (const float*)d_in[2];
    const float* ln1b = (const float*)d_in[3];
    const float* w_in = (const float*)d_in[4];
    const float* b_in = (const float*)d_in[5];
    const float* w_out = (const float*)d_in[6];
    const float* b_out = (const float*)d_in[7];
    const float* ln2w = (const float*)d_in[8];
    const float* ln2b = (const float*)d_in[9];
    const float* w1 = (const float*)d_in[10];
    const float* b1 = (const float*)d_in[11];
    const float* w2 = (const float*)d_in[12];
    const float* b2 = (const float*)d_in[13];
    float* out = (float*)d_out;
    const int E = in_sizes[1] / 2;

    char* ws = (char*)d_ws;
    size_t off = 0;
    auto alloc = [&](size_t bytes) -> void* {
        void* p = ws + off;
        off = (off + bytes + 255) & ~(size_t)255;
        return p;
    };
    uint32* mask1 = (uint32*)alloc((size_t)NN * 128 * 4);
    uint32* mask2 = (uint32*)alloc((size_t)NN * 128 * 4);
    uint32* counts = (uint32*)alloc((size_t)NN * 4);
    uint32* starts = (uint32*)alloc((size_t)NN * 4);
    uint32* cursor = (uint32*)alloc((size_t)NN * 4);
    int* flag = (int*)alloc(256);
    int* cols = (int*)alloc((size_t)(E + NN) * 4);
    unsigned short* w_in_b = (unsigned short*)alloc((size_t)1536 * 512 * 2);
    unsigned short* w_out_b = (unsigned short*)alloc((size_t)512 * 512 * 2);
    unsigned short* w1_b = (unsigned short*)alloc((size_t)2048 * 512 * 2);
    unsigned short* w2_b = (unsigned short*)alloc((size_t)512 * 2048 * 2);
    unsigned short* xn = (unsigned short*)alloc((size_t)NN * DD * 2);
    float* q_f = (float*)alloc((size_t)NN * DD * 4);                   // 8 MiB
    unsigned short* k_b = (unsigned short*)alloc((size_t)NN * DD * 2); // 4 MiB
    unsigned short* v_b = (unsigned short*)alloc((size_t)NN * DD * 2); // 4 MiB
    unsigned short* o_buf = (unsigned short*)alloc((size_t)NN * DD * 2);
    float* x1 = (float*)alloc((size_t)NN * DD * 4);
    unsigned short* xm = (unsigned short*)alloc((size_t)NN * DD * 2);
    // MLP hidden [4096][2048] bf16 (16 MiB) aliases q_f+k_b+v_b (dead after attn)
    unsigned short* h_buf = (unsigned short*)q_f;

    hipMemsetAsync(mask1, 0, (size_t)NN * 128 * 4, stream);
    hipMemsetAsync(mask2, 0, (size_t)NN * 128 * 4, stream);
    hipMemsetAsync(counts, 0, (size_t)NN * 4, stream);

    cvt_all<<<(W_IN_N + W_OUT_N + W1_N + W2_N) / 4 / 256, 256, 0, stream>>>(
        w_in, w_out, w1, w2, w_in_b, w_out_b, w1_b, w2_b);

    detect_i32<<<1, 256, 0, stream>>>((const int*)ei, flag);

    const int tot = E + NN;
    adj_count<<<(tot + 255) / 256, 256, 0, stream>>>(ei, flag, mask1, counts, E);
    ln_rows<<<NN, 256, 0, stream>>>(x, ln1w, ln1b, xn);
    scan_rows<<<1, 1024, 0, stream>>>(counts, starts, cursor);
    adj_fill<<<(tot + 255) / 256, 256, 0, stream>>>(ei, flag, mask2, cursor, cols, E);

    // QKV: [4096,512] @ [1536,512]^T  -> q/k/v in natural [N][512] layout
    gemm_bt<0><<<dim3(12, 32), 256, 0, stream>>>(xn, w_in_b, 512, b_in,
                                                 nullptr, q_f, k_b, v_b);
    attn_sparse<<<NN / 4, 256, 0, stream>>>(q_f, k_b, v_b, cols, starts, counts, o_buf);
    // attn_out + residual: x1 = x + o @ w_out^T + b_out   (256 WGs)
    gemm_bt64<<<dim3(8, 32), 256, 0, stream>>>(o_buf, w_out_b, 512, b_out, x, x1);
    ln_rows<<<NN, 256, 0, stream>>>(x1, ln2w, ln2b, xm);
    // MLP1: relu(xm @ w1^T + b1) -> h (bf16)
    gemm_bt<2><<<dim3(16, 32), 256, 0, stream>>>(xm, w1_b, 512, b1,
                                                 h_buf, nullptr, nullptr, nullptr);
    // MLP2: out = x1 + h @ w2^T + b2   (256 WGs)
    gemm_bt64<<<dim3(8, 32), 256, 0, stream>>>(h_buf, w2_b, 2048, b2, x1, out);
}

// Round 5
// 172.943 us; speedup vs baseline: 1.6332x; 1.0038x over previous
//
#include <hip/hip_runtime.h>

#define NN 4096
#define DD 512
#define HH 8
#define DHH 64

typedef __attribute__((ext_vector_type(8))) __bf16 bfrag;
typedef __attribute__((ext_vector_type(8))) short short8;
typedef __attribute__((ext_vector_type(8))) unsigned short ushort8v;
typedef __attribute__((ext_vector_type(4))) float f32x4;
typedef unsigned int uint32;

// f32 -> bf16 round-to-nearest-even
__device__ __forceinline__ unsigned short f2b(float f) {
    unsigned int u = __builtin_bit_cast(unsigned int, f);
    unsigned int r = 0x7fffu + ((u >> 16) & 1u);
    return (unsigned short)((u + r) >> 16);
}

__device__ __forceinline__ float b2f(unsigned short u) {
    return __builtin_bit_cast(float, (unsigned int)u << 16);
}

__device__ __forceinline__ float fexp2(float x) {
#if __has_builtin(__builtin_amdgcn_exp2f)
    return __builtin_amdgcn_exp2f(x);
#else
    return exp2f(x);
#endif
}

// ---------------- fused weight convert (all 4 weight matrices) ----------------
#define W_IN_N 786432
#define W_OUT_N 262144
#define W1_N 1048576
#define W2_N 1048576
__global__ __launch_bounds__(256) void cvt_all(const float* __restrict__ w_in,
                                               const float* __restrict__ w_out,
                                               const float* __restrict__ w1,
                                               const float* __restrict__ w2,
                                               unsigned short* __restrict__ o_in,
                                               unsigned short* __restrict__ o_out,
                                               unsigned short* __restrict__ o1,
                                               unsigned short* __restrict__ o2) {
    int idx = (blockIdx.x * 256 + threadIdx.x) * 4;
    const float* src;
    unsigned short* dst;
    int off;
    if (idx < W_IN_N) { src = w_in; dst = o_in; off = idx; }
    else if (idx < W_IN_N + W_OUT_N) { src = w_out; dst = o_out; off = idx - W_IN_N; }
    else if (idx < W_IN_N + W_OUT_N + W1_N) { src = w1; dst = o1; off = idx - (W_IN_N + W_OUT_N); }
    else { src = w2; dst = o2; off = idx - (W_IN_N + W_OUT_N + W1_N); }
    float4 v = *reinterpret_cast<const float4*>(src + off);
    ushort4 o;
    o.x = f2b(v.x); o.y = f2b(v.y); o.z = f2b(v.z); o.w = f2b(v.w);
    *reinterpret_cast<ushort4*>(dst + off) = o;
}

// ---------------- edge dtype detect (int64 vs int32) ----------------
__global__ void detect_i32(const int* __restrict__ ei32, int* __restrict__ flag) {
    __shared__ int any;
    if (threadIdx.x == 0) any = 0;
    __syncthreads();
    for (int i = threadIdx.x; i < 1024; i += 256)
        if (ei32[2 * i + 1] != 0) atomicOr(&any, 1);
    __syncthreads();
    if (threadIdx.x == 0) *flag = any;  // 1 -> int32 format, 0 -> int64
}

__device__ __forceinline__ void load_edge(const void* ei, int E, int i, int is32,
                                          int& r, int& c) {
    if (is32) {
        const int* p = (const int*)ei;
        r = p[i]; c = p[E + i];
    } else {
        const long long* p = (const long long*)ei;
        r = (int)p[i]; c = (int)p[E + i];
    }
}

// ---------------- adjacency build (deduped CSR) ----------------
__global__ __launch_bounds__(256) void adj_count(const void* __restrict__ ei,
                                                 const int* __restrict__ flag,
                                                 uint32* __restrict__ mask,
                                                 uint32* __restrict__ counts, int E) {
    int tid = blockIdx.x * 256 + threadIdx.x;
    int total = E + NN;
    if (tid >= total) return;
    int is32 = *flag;
    int r, c;
    if (tid < E) load_edge(ei, E, tid, is32, r, c);
    else { r = tid - E; c = r; }
    uint32 bit = 1u << (c & 31);
    uint32 old = atomicOr(&mask[r * 128 + (c >> 5)], bit);
    if (!(old & bit)) atomicAdd(&counts[r], 1u);
}

__global__ __launch_bounds__(256) void adj_fill(const void* __restrict__ ei,
                                                const int* __restrict__ flag,
                                                uint32* __restrict__ mask2,
                                                uint32* __restrict__ cursor,
                                                int* __restrict__ cols, int E) {
    int tid = blockIdx.x * 256 + threadIdx.x;
    int total = E + NN;
    if (tid >= total) return;
    int is32 = *flag;
    int r, c;
    if (tid < E) load_edge(ei, E, tid, is32, r, c);
    else { r = tid - E; c = r; }
    uint32 bit = 1u << (c & 31);
    uint32 old = atomicOr(&mask2[r * 128 + (c >> 5)], bit);
    if (!(old & bit)) {
        uint32 pos = atomicAdd(&cursor[r], 1u);
        cols[pos] = c;
    }
}

// exclusive scan over 4096 counts
__global__ __launch_bounds__(1024) void scan_rows(const uint32* __restrict__ counts,
                                                  uint32* __restrict__ starts,
                                                  uint32* __restrict__ cursor) {
    __shared__ uint32 tsum[1024];
    int tid = threadIdx.x;
    uint32 c0 = counts[tid * 4], c1 = counts[tid * 4 + 1];
    uint32 c2 = counts[tid * 4 + 2], c3 = counts[tid * 4 + 3];
    tsum[tid] = c0 + c1 + c2 + c3;
    __syncthreads();
    for (int d = 1; d < 1024; d <<= 1) {
        uint32 add = (tid >= d) ? tsum[tid - d] : 0u;
        __syncthreads();
        tsum[tid] += add;
        __syncthreads();
    }
    uint32 base = (tid > 0) ? tsum[tid - 1] : 0u;
    uint32 s0 = base, s1 = base + c0, s2 = s1 + c1, s3 = s2 + c2;
    starts[tid * 4] = s0; starts[tid * 4 + 1] = s1;
    starts[tid * 4 + 2] = s2; starts[tid * 4 + 3] = s3;
    cursor[tid * 4] = s0; cursor[tid * 4 + 1] = s1;
    cursor[tid * 4 + 2] = s2; cursor[tid * 4 + 3] = s3;
}

// ---------------- layernorm: f32 row -> bf16 row ----------------
__global__ __launch_bounds__(256) void ln_rows(const float* __restrict__ x,
                                               const float* __restrict__ w,
                                               const float* __restrict__ b,
                                               unsigned short* __restrict__ out) {
    const int row = blockIdx.x;
    const int tid = threadIdx.x;
    float2 v = reinterpret_cast<const float2*>(x + (size_t)row * DD)[tid];
    float s = v.x + v.y;
    float s2 = v.x * v.x + v.y * v.y;
#pragma unroll
    for (int d = 1; d < 64; d <<= 1) {
        s += __shfl_xor(s, d);
        s2 += __shfl_xor(s2, d);
    }
    __shared__ float red[8];
    if ((tid & 63) == 0) { red[tid >> 6] = s; red[4 + (tid >> 6)] = s2; }
    __syncthreads();
    s = red[0] + red[1] + red[2] + red[3];
    s2 = red[4] + red[5] + red[6] + red[7];
    const float mean = s * (1.f / DD);
    const float var = fmaxf(s2 * (1.f / DD) - mean * mean, 0.f);
    const float rs = rsqrtf(var + 1e-5f);
    const int c = tid * 2;
    out[(size_t)row * DD + c]     = f2b((v.x - mean) * rs * w[c] + b[c]);
    out[(size_t)row * DD + c + 1] = f2b((v.y - mean) * rs * w[c + 1] + b[c + 1]);
}

// ---------------- bf16 MFMA GEMM 128x128: C[M][N] = A @ B^T ----------------
// EPI 0: QKV -> q (f32, scaled) [N][512], k/v (bf16) [N][512]
// EPI 2: out_b[gr*2048+gc] = bf16(relu(acc + bias))
template <int EPI>
__global__ __launch_bounds__(256) void gemm_bt(const unsigned short* __restrict__ A,
                                               const unsigned short* __restrict__ B,
                                               int K,
                                               const float* __restrict__ bias,
                                               unsigned short* __restrict__ out_b,
                                               float* __restrict__ q_out,
                                               unsigned short* __restrict__ k_out,
                                               unsigned short* __restrict__ v_out) {
    __shared__ __align__(16) unsigned short a_lds[128 * 72];
    __shared__ __align__(16) unsigned short b_lds[128 * 72];
    const int tid = threadIdx.x;
    const int lane = tid & 63;
    const int wave = tid >> 6;
    const int wm = wave >> 1, wn = wave & 1;
    const int tm = blockIdx.y, tn = blockIdx.x;

    f32x4 acc[4][4];
#pragma unroll
    for (int mi = 0; mi < 4; ++mi)
#pragma unroll
        for (int ni = 0; ni < 4; ++ni) acc[mi][ni] = (f32x4){0.f, 0.f, 0.f, 0.f};

    const size_t a_base = (size_t)(tm * 128) * K;
    const size_t b_base = (size_t)(tn * 128) * K;

    for (int k0 = 0; k0 < K; k0 += 64) {
        __syncthreads();
#pragma unroll
        for (int it = 0; it < 4; ++it) {
            int slot = tid + 256 * it;
            int row = slot >> 3;
            int cs = (slot & 7) << 3;
            short8 va = *reinterpret_cast<const short8*>(A + a_base + (size_t)row * K + k0 + cs);
            short8 vb = *reinterpret_cast<const short8*>(B + b_base + (size_t)row * K + k0 + cs);
            *reinterpret_cast<short8*>(&a_lds[row * 72 + cs]) = va;
            *reinterpret_cast<short8*>(&b_lds[row * 72 + cs]) = vb;
        }
        __syncthreads();
#pragma unroll
        for (int ks = 0; ks < 2; ++ks) {
            const int kc = ((lane >> 4) << 3) + (ks << 5);
            bfrag af[4], bfr[4];
#pragma unroll
            for (int mi = 0; mi < 4; ++mi)
                af[mi] = *reinterpret_cast<const bfrag*>(
                    &a_lds[(wm * 64 + mi * 16 + (lane & 15)) * 72 + kc]);
#pragma unroll
            for (int ni = 0; ni < 4; ++ni)
                bfr[ni] = *reinterpret_cast<const bfrag*>(
                    &b_lds[(wn * 64 + ni * 16 + (lane & 15)) * 72 + kc]);
#pragma unroll
            for (int mi = 0; mi < 4; ++mi)
#pragma unroll
                for (int ni = 0; ni < 4; ++ni)
                    acc[mi][ni] = __builtin_amdgcn_mfma_f32_16x16x32_bf16(
                        af[mi], bfr[ni], acc[mi][ni], 0, 0, 0);
        }
    }

    const int r0 = (lane >> 4) << 2;
    const int cl = lane & 15;
#pragma unroll
    for (int mi = 0; mi < 4; ++mi) {
#pragma unroll
        for (int ni = 0; ni < 4; ++ni) {
#pragma unroll
            for (int r = 0; r < 4; ++r) {
                int gr = tm * 128 + wm * 64 + mi * 16 + r0 + r;
                int gc = tn * 128 + wn * 64 + ni * 16 + cl;
                float v = acc[mi][ni][r] + bias[gc];
                if (EPI == 0) {
                    if (gc < 512) {
                        // fold score scale (1/sqrt(64)) and log2(e) into q
                        q_out[(size_t)gr * 512 + gc] = v * 0.18033688011112042f;
                    } else if (gc < 1024) {
                        k_out[(size_t)gr * 512 + (gc - 512)] = f2b(v);
                    } else {
                        v_out[(size_t)gr * 512 + (gc - 1024)] = f2b(v);
                    }
                } else {
                    out_b[(size_t)gr * 2048 + gc] = f2b(fmaxf(v, 0.f));
                }
            }
        }
    }
}

// ---------------- bf16 MFMA GEMM 128x64: out = acc + bias + resid (N=512 out) --
__global__ __launch_bounds__(256) void gemm_bt64(const unsigned short* __restrict__ A,
                                                 const unsigned short* __restrict__ B,
                                                 int K,
                                                 const float* __restrict__ bias,
                                                 const float* __restrict__ resid,
                                                 float* __restrict__ out_f) {
    __shared__ __align__(16) unsigned short a_lds[128 * 72];
    __shared__ __align__(16) unsigned short b_lds[64 * 72];
    const int tid = threadIdx.x;
    const int lane = tid & 63;
    const int wave = tid >> 6;
    const int wm = wave >> 1, wn = wave & 1;
    const int tm = blockIdx.y, tn = blockIdx.x;

    f32x4 acc[4][2];
#pragma unroll
    for (int mi = 0; mi < 4; ++mi)
#pragma unroll
        for (int ni = 0; ni < 2; ++ni) acc[mi][ni] = (f32x4){0.f, 0.f, 0.f, 0.f};

    const size_t a_base = (size_t)(tm * 128) * K;
    const size_t b_base = (size_t)(tn * 64) * K;

    for (int k0 = 0; k0 < K; k0 += 64) {
        __syncthreads();
#pragma unroll
        for (int it = 0; it < 4; ++it) {
            int slot = tid + 256 * it;      // A: 128 rows x 8 chunks
            int row = slot >> 3;
            int cs = (slot & 7) << 3;
            *reinterpret_cast<short8*>(&a_lds[row * 72 + cs]) =
                *reinterpret_cast<const short8*>(A + a_base + (size_t)row * K + k0 + cs);
        }
#pragma unroll
        for (int it = 0; it < 2; ++it) {
            int slot = tid + 256 * it;      // B: 64 rows x 8 chunks
            int row = slot >> 3;
            int cs = (slot & 7) << 3;
            *reinterpret_cast<short8*>(&b_lds[row * 72 + cs]) =
                *reinterpret_cast<const short8*>(B + b_base + (size_t)row * K + k0 + cs);
        }
        __syncthreads();
#pragma unroll
        for (int ks = 0; ks < 2; ++ks) {
            const int kc = ((lane >> 4) << 3) + (ks << 5);
            bfrag af[4], bfr[2];
#pragma unroll
            for (int mi = 0; mi < 4; ++mi)
                af[mi] = *reinterpret_cast<const bfrag*>(
                    &a_lds[(wm * 64 + mi * 16 + (lane & 15)) * 72 + kc]);
#pragma unroll
            for (int ni = 0; ni < 2; ++ni)
                bfr[ni] = *reinterpret_cast<const bfrag*>(
                    &b_lds[(wn * 32 + ni * 16 + (lane & 15)) * 72 + kc]);
#pragma unroll
            for (int mi = 0; mi < 4; ++mi)
#pragma unroll
                for (int ni = 0; ni < 2; ++ni)
                    acc[mi][ni] = __builtin_amdgcn_mfma_f32_16x16x32_bf16(
                        af[mi], bfr[ni], acc[mi][ni], 0, 0, 0);
        }
    }

    const int r0 = (lane >> 4) << 2;
    const int cl = lane & 15;
#pragma unroll
    for (int mi = 0; mi < 4; ++mi) {
#pragma unroll
        for (int ni = 0; ni < 2; ++ni) {
#pragma unroll
            for (int r = 0; r < 4; ++r) {
                int gr = tm * 128 + wm * 64 + mi * 16 + r0 + r;
                int gc = tn * 64 + wn * 32 + ni * 16 + cl;
                out_f[(size_t)gr * 512 + gc] =
                    acc[mi][ni][r] + bias[gc] + resid[(size_t)gr * 512 + gc];
            }
        }
    }
}

// ---------------- sparse masked attention: all 8 heads fused per wave --------
// wave per query. lane = (h, t): h = lane>>3 (head), t = lane&7 (dims 8t..8t+8).
// Per neighbor: ONE coalesced 1KB row load serves all heads (addr = col*1024 +
// lane*16, SGPR base via uniform readlane broadcast of col). Two-pass over
// bodies of 8 neighbors; scores live in statically-indexed registers; softmax
// state per head computed redundantly in-lane (no cross-group reductions); each
// lane exclusively owns output dims -> no O reduction, coalesced 1KB store.
__global__ __launch_bounds__(256) void attn_sparse(const float* __restrict__ qf,
                                                   const unsigned short* __restrict__ kb,
                                                   const unsigned short* __restrict__ vb,
                                                   const int* __restrict__ cols,
                                                   const uint32* __restrict__ starts,
                                                   const uint32* __restrict__ counts,
                                                   unsigned short* __restrict__ o_buf) {
    const int lane = threadIdx.x & 63;
    const int wid = threadIdx.x >> 6;
    const int q = blockIdx.x * 4 + wid;

    const float4* qp = reinterpret_cast<const float4*>(qf + (size_t)q * DD + lane * 8);
    const float4 q0 = qp[0], q1 = qp[1];

    const int cnt = (int)counts[q];
    const int base = (int)starts[q];

    float m_run = -3.0e38f, l_run = 0.f;
    float oa[8];
#pragma unroll
    for (int i = 0; i < 8; ++i) oa[i] = 0.f;

    for (int cc = 0; cc < cnt; cc += 64) {
        const int clen = min(64, cnt - cc);
        const int colv = (lane < clen) ? cols[base + cc + lane] : 0;

        for (int j0 = 0; j0 < clen; j0 += 8) {
            float s_arr[8];
            int col_arr[8];
            // ---- pass 1: scores for 8 neighbors (8 independent 1KB gathers) --
#pragma unroll
            for (int u = 0; u < 8; ++u) {
                const int col = __shfl(colv, j0 + u);   // uniform -> readlane
                col_arr[u] = col;
                const bool act = (j0 + u) < clen;
                ushort8v kq = *reinterpret_cast<const ushort8v*>(
                    kb + (size_t)col * DD + lane * 8);
                float d = q0.x * b2f(kq[0]);
                d = fmaf(q0.y, b2f(kq[1]), d);
                d = fmaf(q0.z, b2f(kq[2]), d);
                d = fmaf(q0.w, b2f(kq[3]), d);
                d = fmaf(q1.x, b2f(kq[4]), d);
                d = fmaf(q1.y, b2f(kq[5]), d);
                d = fmaf(q1.z, b2f(kq[6]), d);
                d = fmaf(q1.w, b2f(kq[7]), d);
                // reduce across the 8 lanes of this head
                d += __shfl_xor(d, 1);
                d += __shfl_xor(d, 2);
                d += __shfl_xor(d, 4);
                s_arr[u] = act ? d : -3.0e38f;
            }
            float mloc = fmaxf(fmaxf(fmaxf(s_arr[0], s_arr[1]), fmaxf(s_arr[2], s_arr[3])),
                               fmaxf(fmaxf(s_arr[4], s_arr[5]), fmaxf(s_arr[6], s_arr[7])));
            if (mloc > m_run) {                 // defer-rescale: alpha==1 otherwise
                const float alpha = fexp2(m_run - mloc);
                l_run *= alpha;
#pragma unroll
                for (int i = 0; i < 8; ++i) oa[i] *= alpha;
                m_run = mloc;
            }
            // ---- pass 2: exp + PV (no shuffles) ----
#pragma unroll
            for (int u = 0; u < 8; ++u) {
                const float p = fexp2(s_arr[u] - m_run);  // inactive -> 0
                l_run += p;
                ushort8v vq = *reinterpret_cast<const ushort8v*>(
                    vb + (size_t)col_arr[u] * DD + lane * 8);
#pragma unroll
                for (int i = 0; i < 8; ++i) oa[i] = fmaf(p, b2f(vq[i]), oa[i]);
            }
        }
    }

    const float rl = 1.f / l_run;
    ushort8v ov;
#pragma unroll
    for (int i = 0; i < 8; ++i) ov[i] = f2b(oa[i] * rl);
    *reinterpret_cast<ushort8v*>(o_buf + (size_t)q * DD + lane * 8) = ov;
}

// ---------------- launch ----------------
extern "C" void kernel_launch(void* const* d_in, const int* in_sizes, int n_in,
                              void* d_out, int out_size, void* d_ws, size_t ws_size,
                              hipStream_t stream) {
    const float* x = (const float*)d_in[0];
    const void* ei = d_in[1];
    const float* ln1w = (const float*)d_in[2];
    const float* ln1b = (const float*)d_in[3];
    const float* w_in = (const float*)d_in[4];
    const float* b_in = (const float*)d_in[5];
    const float* w_out = (const float*)d_in[6];
    const float* b_out = (const float*)d_in[7];
    const float* ln2w = (const float*)d_in[8];
    const float* ln2b = (const float*)d_in[9];
    const float* w1 = (const float*)d_in[10];
    const float* b1 = (const float*)d_in[11];
    const float* w2 = (const float*)d_in[12];
    const float* b2 = (const float*)d_in[13];
    float* out = (float*)d_out;
    const int E = in_sizes[1] / 2;

    char* ws = (char*)d_ws;
    size_t off = 0;
    auto alloc = [&](size_t bytes) -> void* {
        void* p = ws + off;
        off = (off + bytes + 255) & ~(size_t)255;
        return p;
    };
    uint32* mask1 = (uint32*)alloc((size_t)NN * 128 * 4);
    uint32* mask2 = (uint32*)alloc((size_t)NN * 128 * 4);
    uint32* counts = (uint32*)alloc((size_t)NN * 4);
    uint32* starts = (uint32*)alloc((size_t)NN * 4);
    uint32* cursor = (uint32*)alloc((size_t)NN * 4);
    int* flag = (int*)alloc(256);
    int* cols = (int*)alloc((size_t)(E + NN) * 4);
    unsigned short* w_in_b = (unsigned short*)alloc((size_t)1536 * 512 * 2);
    unsigned short* w_out_b = (unsigned short*)alloc((size_t)512 * 512 * 2);
    unsigned short* w1_b = (unsigned short*)alloc((size_t)2048 * 512 * 2);
    unsigned short* w2_b = (unsigned short*)alloc((size_t)512 * 2048 * 2);
    unsigned short* xn = (unsigned short*)alloc((size_t)NN * DD * 2);
    float* q_f = (float*)alloc((size_t)NN * DD * 4);                   // 8 MiB
    unsigned short* k_b = (unsigned short*)alloc((size_t)NN * DD * 2); // 4 MiB
    unsigned short* v_b = (unsigned short*)alloc((size_t)NN * DD * 2); // 4 MiB
    unsigned short* o_buf = (unsigned short*)alloc((size_t)NN * DD * 2);
    float* x1 = (float*)alloc((size_t)NN * DD * 4);
    unsigned short* xm = (unsigned short*)alloc((size_t)NN * DD * 2);
    // MLP hidden [4096][2048] bf16 (16 MiB) aliases q_f+k_b+v_b (dead after attn)
    unsigned short* h_buf = (unsigned short*)q_f;

    hipMemsetAsync(mask1, 0, (size_t)NN * 128 * 4, stream);
    hipMemsetAsync(mask2, 0, (size_t)NN * 128 * 4, stream);
    hipMemsetAsync(counts, 0, (size_t)NN * 4, stream);

    cvt_all<<<(W_IN_N + W_OUT_N + W1_N + W2_N) / 4 / 256, 256, 0, stream>>>(
        w_in, w_out, w1, w2, w_in_b, w_out_b, w1_b, w2_b);

    detect_i32<<<1, 256, 0, stream>>>((const int*)ei, flag);

    const int tot = E + NN;
    adj_count<<<(tot + 255) / 256, 256, 0, stream>>>(ei, flag, mask1, counts, E);
    ln_rows<<<NN, 256, 0, stream>>>(x, ln1w, ln1b, xn);
    scan_rows<<<1, 1024, 0, stream>>>(counts, starts, cursor);
    adj_fill<<<(tot + 255) / 256, 256, 0, stream>>>(ei, flag, mask2, cursor, cols, E);

    // QKV: [4096,512] @ [1536,512]^T  -> q/k/v in natural [N][512] layout
    gemm_bt<0><<<dim3(12, 32), 256, 0, stream>>>(xn, w_in_b, 512, b_in,
                                                 nullptr, q_f, k_b, v_b);
    attn_sparse<<<NN / 4, 256, 0, stream>>>(q_f, k_b, v_b, cols, starts, counts, o_buf);
    // attn_out + residual: x1 = x + o @ w_out^T + b_out   (256 WGs)
    gemm_bt64<<<dim3(8, 32), 256, 0, stream>>>(o_buf, w_out_b, 512, b_out, x, x1);
    ln_rows<<<NN, 256, 0, stream>>>(x1, ln2w, ln2b, xm);
    // MLP1: relu(xm @ w1^T + b1) -> h (bf16)
    gemm_bt<2><<<dim3(16, 32), 256, 0, stream>>>(xm, w1_b, 512, b1,
                                                 h_buf, nullptr, nullptr, nullptr);
    // MLP2: out = x1 + h @ w2^T + b2   (256 WGs)
    gemm_bt64<<<dim3(8, 32), 256, 0, stream>>>(h_buf, w2_b, 2048, b2, x1, out);
}